// Round 6
// baseline (214.966 us; speedup 1.0000x reference)
//
#include <hip/hip_runtime.h>
#include <math.h>

// Problem constants (reference: T,B,E,H = 1024,4,1024,16; DH=64; 32 buckets, max_dist 128)
#define T_ 1024
#define B_ 4
#define E_ 1024
#define H_ 16
#define DH_ 64

#define LOG2E 1.44269504088896f

typedef __attribute__((ext_vector_type(8))) __bf16 bf16x8;
typedef __attribute__((ext_vector_type(4))) __bf16 bf16x4;
typedef __attribute__((ext_vector_type(4))) float f32x4;

// fp32 -> bf16 round-to-nearest-even
__device__ __forceinline__ __bf16 f2bf(float x){
  union { unsigned short u; __bf16 b; } cv;
  unsigned u32 = __float_as_uint(x);
  cv.u = (unsigned short)((u32 + 0x7fffu + ((u32 >> 16) & 1u)) >> 16);
  return cv.b;
}
// fp32 -> bf16 round-half-up (cheaper; used only for P >= 0)
__device__ __forceinline__ __bf16 f2bf_fast(float x){
  union { unsigned short u; __bf16 b; } cv;
  cv.u = (unsigned short)((__float_as_uint(x) + 0x8000u) >> 16);
  return cv.b;
}

// async global->LDS, 16B per lane; LDS dest is wave-uniform base + lane*16 (m97/m104)
__device__ __forceinline__ void glds16(const void* g, void* l){
  __builtin_amdgcn_global_load_lds(
      (__attribute__((address_space(1))) void*)(void*)g,
      (__attribute__((address_space(3))) void*)l,
      16, 0, 0);
}

#define PBAR() do { asm volatile("" ::: "memory"); __builtin_amdgcn_s_barrier(); asm volatile("" ::: "memory"); } while(0)
#define VDRAIN() asm volatile("s_waitcnt vmcnt(0)" ::: "memory")

// ---------------- prep: weight cvt (blocks 0..4095) + gates/qbf (4096..4351) + tab (4352..4479) ----------------
__global__ __launch_bounds__(256) void prep_kernel(
    const float* __restrict__ q_w, const float* __restrict__ k_w,
    const float* __restrict__ v_w, const float* __restrict__ out_w,
    __bf16* __restrict__ wq, __bf16* __restrict__ wk,
    __bf16* __restrict__ wv, __bf16* __restrict__ wo,
    const float* __restrict__ query, const float* __restrict__ gw,
    const float* __restrict__ gb, const float* __restrict__ ga,
    float* __restrict__ gates, __bf16* __restrict__ qbf,
    const float* __restrict__ rel_bias, float* __restrict__ tab)
{
  const int bid = blockIdx.x;
  const int tid = threadIdx.x;
  if (bid < 4096){
    const float* a; __bf16* o;
    switch (bid >> 10){
      case 0: a = q_w;  o = wq; break;
      case 1: a = k_w;  o = wk; break;
      case 2: a = v_w;  o = wv; break;
      default: a = out_w; o = wo; break;
    }
    int i = ((bid & 1023) * 256 + tid) * 4;
    float4 v = *(const float4*)(a + i);
    bf16x4 r;
    r[0] = f2bf(v.x); r[1] = f2bf(v.y); r[2] = f2bf(v.z); r[3] = f2bf(v.w);
    *(bf16x4*)(o + i) = r;
  } else if (bid < 4352){
    int t = (bid - 4096) * 4 + (tid >> 6);
    int bh = tid & 63;
    int h = bh & 15;
    const float* q = query + (size_t)t * E_ * B_ + bh * 64;
    __bf16* qo = qbf + (size_t)t * E_ * B_ + bh * 64;
    float g[8];
    #pragma unroll
    for (int e = 0; e < 8; e++) g[e] = gb[e];
    #pragma unroll
    for (int c = 0; c < 8; c++){
      float4 v0 = *(const float4*)(q + c * 8);
      float4 v1 = *(const float4*)(q + c * 8 + 4);
      bf16x8 o;
      o[0] = f2bf(v0.x); o[1] = f2bf(v0.y); o[2] = f2bf(v0.z); o[3] = f2bf(v0.w);
      o[4] = f2bf(v1.x); o[5] = f2bf(v1.y); o[6] = f2bf(v1.z); o[7] = f2bf(v1.w);
      *(bf16x8*)(qo + c * 8) = o;
      #pragma unroll
      for (int e = 0; e < 8; e++){
        const float* w = gw + e * 64 + c * 8;     // uniform -> s_load
        g[e] += v0.x * w[0] + v0.y * w[1] + v0.z * w[2] + v0.w * w[3]
              + v1.x * w[4] + v1.y * w[5] + v1.z * w[6] + v1.w * w[7];
      }
    }
    float a0 = (g[0] + g[1]) + (g[2] + g[3]);
    float a1 = (g[4] + g[5]) + (g[6] + g[7]);
    float sa = 1.f / (1.f + __expf(-a0));
    float sb = 1.f / (1.f + __expf(-a1));
    gates[bh * T_ + t] = (sa * (sb * ga[h] - 1.0f) + 2.0f) * LOG2E;   // pre-scaled for exp2
  } else {
    int tb = bid - 4352;               // 0..127
    int h = tb >> 3;
    int i = (tb & 7) * 256 + tid;
    if (i < 2047){
      int rp = i - 1023;
      int base = rp > 0 ? 16 : 0;
      int arp = rp < 0 ? -rp : rp;
      int off;
      if (arp < 8) off = arp;
      else {
        float val = (logf((float)arp * 0.125f) / 2.772588722239781f) * 8.0f;
        int lg = (int)val;
        off = 8 + (lg > 7 ? 7 : lg);
      }
      tab[h * 2047 + i] = rel_bias[(base + off) * H_ + h];   // fp32 now
    }
  }
}

// ---------------- fused QKV GEMM v5: 4096 x 3072 x 1024 (B = [Wq|Wk|Wv]), 256x256 tile ----------------
// 8-phase-class schedule (T3+T4+T5, m201 structure): 8 waves (2m x 4n, per-wave 128x64), BK=64,
// dbuf LDS 128 KB, per K-tile 4 phases {ds_read subtile | 2 glds16 | barrier | setprio+16 MFMA | barrier},
// single counted drain after P3's MFMA (A-halves staged earliest -> max latency cover).
// Grid 192 = 16m x 12n; each block z-uniform (BN=256 divides 1024). Accumulation order identical to v4.
__global__ __launch_bounds__(512, 2) void gemm_qkv(
    const __bf16* __restrict__ A,
    const __bf16* __restrict__ W0, const __bf16* __restrict__ W1, const __bf16* __restrict__ W2,
    const float* __restrict__ b0, const float* __restrict__ b1, const float* __restrict__ b2,
    __bf16* out0, __bf16* out1, __bf16* out2)
{
  __shared__ __bf16 smem[65536];       // 128 KB: As[2][256*64] | Bs[2][256*64]; reused as vbuf in v-epilogue
  const int tid = threadIdx.x;
  const int lane = tid & 63, wid = tid >> 6;   // 8 waves
  const int l15 = lane & 15, quad = lane >> 4;
  const int wr = wid >> 2, wc = wid & 3;       // wave grid 2m x 4n
  const int dd = blockIdx.x;                   // 0..191
  const int j = dd >> 3;                       // 0..23
  const int bm = (dd & 7) * 2 + (j & 1);       // 0..15, m fast within XCD -> A-slab L2 reuse
  const int bnb = j >> 1;                      // 0..11
  const int m0 = bm * 256;
  const int n0 = bnb * 256;
  const int z  = n0 >> 10;                     // 0=q, 1=k, 2=v (block-uniform)
  const int nz = n0 & 1023;                    // col offset within z-matrix
  const __bf16* Wp = (z == 0 ? W0 : (z == 1 ? W1 : W2)) + (size_t)nz * E_;

  const int grow = lane >> 3;
  const int gcol = (((lane & 7) ^ grow) * 8);  // XOR-swizzled source chunk
  const int sw = (l15 & 7);                    // frag-read swizzle key

  f32x4 acc[8][4];
  #pragma unroll
  for (int i = 0; i < 8; i++)
    #pragma unroll
    for (int jj = 0; jj < 4; jj++){
      acc[i][jj][0] = 0.f; acc[i][jj][1] = 0.f; acc[i][jj][2] = 0.f; acc[i][jj][3] = 0.f;
    }

  auto SA = [&](int nb, int kn, int r){        // stage 8 A-rows (wave-uniform dest)
    const int rb = wid * 32 + r * 8;
    glds16(A + (size_t)(m0 + rb + grow) * E_ + kn + gcol, smem + nb * 16384 + rb * 64);
  };
  auto SB = [&](int nb, int kn, int r){        // stage 8 B-rows
    const int rb = wid * 32 + r * 8;
    glds16(Wp + (size_t)(rb + grow) * E_ + kn + gcol, smem + 32768 + nb * 16384 + rb * 64);
  };

  bf16x8 am[4], bnr[4];
  auto RDA = [&](const __bf16* Ac, int mh, int kq){
    const int ce = ((kq * 4 + quad) ^ sw) * 8;
    #pragma unroll
    for (int i = 0; i < 4; i++)
      am[i] = *(const bf16x8*)&Ac[(wr * 128 + mh * 64 + i * 16 + l15) * 64 + ce];
  };
  auto RDB = [&](const __bf16* Bc, int kq){
    const int ce = ((kq * 4 + quad) ^ sw) * 8;
    #pragma unroll
    for (int jj = 0; jj < 4; jj++)
      bnr[jj] = *(const bf16x8*)&Bc[(wc * 64 + jj * 16 + l15) * 64 + ce];
  };
  auto MM = [&](int mh){
    __builtin_amdgcn_s_setprio(1);
    #pragma unroll
    for (int i = 0; i < 4; i++)
      #pragma unroll
      for (int jj = 0; jj < 4; jj++)
        acc[mh * 4 + i][jj] = __builtin_amdgcn_mfma_f32_16x16x32_bf16(am[i], bnr[jj], acc[mh * 4 + i][jj], 0, 0, 0);
    __builtin_amdgcn_s_setprio(0);
  };

  // prologue: stage K-tile 0 into buf 0, full drain
  #pragma unroll
  for (int r = 0; r < 4; r++){ SA(0, 0, r); SB(0, 0, r); }
  VDRAIN();
  PBAR();

  for (int t = 0; t < 16; t++){
    const int cb_ = (t & 1) * 16384;
    const __bf16* Ac = smem + cb_;
    const __bf16* Bc = smem + 32768 + cb_;
    const int nb = (t & 1) ^ 1;
    const int kn = (t + 1) * 64;
    const bool pf = (t < 15);
    // P0: mh0/kq0 + stage A-half0(next)
    RDA(Ac, 0, 0); RDB(Bc, 0);
    if (pf){ SA(nb, kn, 0); SA(nb, kn, 1); }
    PBAR();
    MM(0);
    PBAR();
    // P1: mh1/kq0 (bn reused) + stage A-half1(next)
    RDA(Ac, 1, 0);
    if (pf){ SA(nb, kn, 2); SA(nb, kn, 3); }
    PBAR();
    MM(1);
    PBAR();
    // P2: mh0/kq1 + stage B-half0(next)
    RDA(Ac, 0, 1); RDB(Bc, 1);
    if (pf){ SB(nb, kn, 0); SB(nb, kn, 1); }
    PBAR();
    MM(0);
    PBAR();
    // P3: mh1/kq1 (bn reused) + stage B-half1(next); counted drain after MFMA
    RDA(Ac, 1, 1);
    if (pf){ SB(nb, kn, 2); SB(nb, kn, 3); }
    PBAR();
    MM(1);
    if (pf) VDRAIN();
    PBAR();
  }

  if (z < 2){
    // q/k epilogue: out[((bb*H + nt)*T + t)*DH + d2]; nt wave-uniform (= nz/64 + wc)
    __bf16* outp = z ? out1 : out0;
    const float* bias = z ? b1 : b0;
    const float scale = z ? 1.0f : 0.125f * LOG2E;
    const int nt = (nz >> 6) + wc;
    #pragma unroll
    for (int nf = 0; nf < 4; nf++){
      const int d2 = nf * 16 + l15;
      const float bc = bias[nt * 64 + d2];
      #pragma unroll
      for (int mf = 0; mf < 8; mf++){
        const int tb = (m0 + wr * 128 + mf * 16 + quad * 4) >> 2;   // base%4==0 -> bb = r
        #pragma unroll
        for (int r = 0; r < 4; r++){
          float v = (acc[mf][nf][r] + bc) * scale;
          outp[(size_t)((r * H_ + nt) * T_ + tb) * DH_ + d2] = f2bf(v);
        }
      }
    }
  } else {
    // v epilogue: transpose via LDS (smem reuse, 128 KB = [256][4][64])
    __bf16 (*vbuf)[4][64] = (__bf16 (*)[4][64])smem;
    #pragma unroll
    for (int nf = 0; nf < 4; nf++){
      const int cbn = wc * 64 + nf * 16 + l15;     // col in block 0..255
      const float bc = b2[nz + cbn];
      #pragma unroll
      for (int mf = 0; mf < 8; mf++){
        const int tl = wr * 32 + mf * 4 + quad;    // local t 0..63
        #pragma unroll
        for (int r = 0; r < 4; r++)
          vbuf[cbn][r][tl] = f2bf(acc[mf][nf][r] + bc);
      }
    }
    PBAR();
    #pragma unroll
    for (int s = 0; s < 2; s++){
      const int job = s * 512 + tid;               // 1024 (col, bb) jobs
      const int vc = job >> 2, bb = job & 3;
      const int nt = (nz >> 6) + (vc >> 6), d = vc & 63;
      __bf16* dst = out2 + (size_t)((bb * H_ + nt) * DH_ + d) * T_ + (m0 >> 2);
      const __bf16* src = &vbuf[vc][bb][0];
      #pragma unroll
      for (int c = 0; c < 8; c++)
        *(bf16x8*)(dst + c * 8) = *(const bf16x8*)(src + c * 8);
    }
  }
}

// ---------------- out-proj GEMM: 64x128 tile, BK=64, XOR-swizzled LDS, XCD grid (512), fp32 write ----------------
__global__ __launch_bounds__(256) void gemm_out(
    const __bf16* __restrict__ A, const __bf16* __restrict__ W,
    const float* __restrict__ bias, float* __restrict__ out)
{
  __shared__ __bf16 As[64 * 64];
  __shared__ __bf16 Bs[128 * 64];
  const int tid = threadIdx.x;
  const int lane = tid & 63, wid = tid >> 6;
  const int l15 = lane & 15, quad = lane >> 4;
  const int wm = wid >> 1, wn = wid & 1;
  const int dd = blockIdx.x;
  const int j = dd >> 3;
  const int m0 = ((dd & 7) * 8 + (j & 7)) * 64;
  const int n0 = (j >> 3) * 128;

  f32x4 acc[2][4];
  #pragma unroll
  for (int i = 0; i < 2; i++)
    #pragma unroll
    for (int jj = 0; jj < 4; jj++){
      acc[i][jj][0] = 0.f; acc[i][jj][1] = 0.f; acc[i][jj][2] = 0.f; acc[i][jj][3] = 0.f;
    }

  const int grow = lane >> 3;
  const int gcol = (((lane & 7) ^ grow) * 8);
  const int sw = (l15 & 7);

  for (int k0 = 0; k0 < E_; k0 += 64){
    __syncthreads();
    #pragma unroll
    for (int r = 0; r < 2; r++){
      int rbA = wid * 16 + r * 8;
      glds16(A + (size_t)(m0 + rbA + grow) * E_ + k0 + gcol, &As[rbA * 64]);
    }
    #pragma unroll
    for (int r = 0; r < 4; r++){
      int rbB = wid * 32 + r * 8;
      glds16(W + (size_t)(n0 + rbB + grow) * E_ + k0 + gcol, &Bs[rbB * 64]);
    }
    __syncthreads();
    #pragma unroll
    for (int kq = 0; kq < 2; kq++){
      const int ce = ((kq * 4 + quad) ^ sw) * 8;
      bf16x8 am[2], bn[4];
      #pragma unroll
      for (int i = 0; i < 2; i++) am[i] = *(const bf16x8*)&As[(wm * 32 + i * 16 + l15) * 64 + ce];
      #pragma unroll
      for (int jj = 0; jj < 4; jj++) bn[jj] = *(const bf16x8*)&Bs[(wn * 64 + jj * 16 + l15) * 64 + ce];
      #pragma unroll
      for (int i = 0; i < 2; i++)
        #pragma unroll
        for (int jj = 0; jj < 4; jj++)
          acc[i][jj] = __builtin_amdgcn_mfma_f32_16x16x32_bf16(am[i], bn[jj], acc[i][jj], 0, 0, 0);
    }
  }

  #pragma unroll
  for (int i = 0; i < 2; i++){
    const int row0 = m0 + wm * 32 + i * 16 + quad * 4;
    #pragma unroll
    for (int jj = 0; jj < 4; jj++){
      const int col = n0 + wn * 64 + jj * 16 + l15;
      const float bc = bias[col];
      #pragma unroll
      for (int r = 0; r < 4; r++)
        out[(size_t)(row0 + r) * E_ + col] = acc[i][jj][r] + bc;
    }
  }
}

// ---------------- flash attention v6: 128 t per block, 256 thr (4 waves), 2 blocks/CU ----------------
// Double-buffered K/V DMA (depth-1 pipeline); ONE __syncthreads per tile.
__global__ __launch_bounds__(256) void attn_kernel(
    const __bf16* __restrict__ qg, const __bf16* __restrict__ kg, const __bf16* __restrict__ vgT,
    const float* __restrict__ gates, const float* __restrict__ tab,
    __bf16* __restrict__ ctx)
{
  const int LDP = 72;                  // P rows padded (written by VALU, b64/b128 path)
  __shared__ __bf16 Ks[2][64 * 64];    // 2 x 8 KB, swizzled chunks: slot c holds global chunk c^(row&7)
  __shared__ __bf16 Vt[2][64 * 64];    // 2 x 8 KB, swizzled (rows = d, cols = s)
  __shared__ __bf16 Pt[4][2][16 * LDP];// per-(wave, tg) P^T
  __shared__ float tabh[2048];         // fp32 rel-bias row for this h

  const int tid = threadIdx.x;
  const int lane = tid & 63, wid = tid >> 6;       // 4 waves
  const int l15 = lane & 15, quad = lane >> 4;
  // XCD swizzle: all 8 t-blocks of a bh share XCD slot d&7
  const int dgrid = blockIdx.x;
  const int j = dgrid >> 3;
  const int bh = (dgrid & 7) + 8 * (j & 7);
  const int tq = j >> 3;               // 0..7 -> t-base tq*128
  const int b = bh >> 4, h = bh & 15;
  const __bf16* qb = qg + (size_t)bh * T_ * DH_;
  const __bf16* kb = kg + (size_t)bh * T_ * DH_;
  const __bf16* vb = vgT + (size_t)bh * DH_ * T_;

  for (int i = tid; i < 2047; i += 256) tabh[i] = tab[h * 2047 + i];

  const int t0w = tq * 128 + wid * 32; // wave owns 32 t = 2 groups of 16
  bf16x8 bq[2][2];
  float g[2];
  int ibase[2];
  #pragma unroll
  for (int tg = 0; tg < 2; tg++){
    int t_lane = t0w + tg * 16 + l15;
    bq[tg][0] = *(const bf16x8*)(qb + (size_t)t_lane * DH_ + quad * 8);
    bq[tg][1] = *(const bf16x8*)(qb + (size_t)t_lane * DH_ + 32 + quad * 8);
    g[tg] = gates[bh * T_ + t_lane];   // already * log2e
    ibase[tg] = 1023 - t_lane;
  }

  const int grow = lane >> 3;                  // staging row within 8-row group
  const int gcol = (((lane & 7) ^ grow) * 8);  // XOR-swizzled source chunk
  const int swf = (l15 & 7);                   // frag-read swizzle key

  float l_run[2] = {0.f, 0.f};
  f32x4 O[2][4];
  #pragma unroll
  for (int tg = 0; tg < 2; tg++)
    #pragma unroll
    for (int mt = 0; mt < 4; mt++){ O[tg][mt][0]=0.f; O[tg][mt][1]=0.f; O[tg][mt][2]=0.f; O[tg][mt][3]=0.f; }

  // prologue: stage s-tile 0 into buffer 0 (wave stages rows [wid*16, wid*16+16))
  #pragma unroll
  for (int r = 0; r < 2; r++){
    int rb = wid * 16 + r * 8;
    glds16(kb + (size_t)(rb + grow) * DH_ + gcol, &Ks[0][rb * 64]);
    glds16(vb + (size_t)(rb + grow) * T_ + gcol, &Vt[0][rb * 64]);
  }
  __syncthreads();                     // implicit vmcnt(0): tile 0 staged

  for (int it = 0; it < 16; it++){
    const int s0 = it * 64;
    const int cur = it & 1;

    // issue next tile's DMA into the other buffer (overlaps with compute below)
    if (it < 15){
      const int sn = s0 + 64;
      #pragma unroll
      for (int r = 0; r < 2; r++){
        int rb = wid * 16 + r * 8;
        glds16(kb + (size_t)(sn + rb + grow) * DH_ + gcol, &Ks[cur ^ 1][rb * 64]);
        glds16(vb + (size_t)(rb + grow) * T_ + sn + gcol, &Vt[cur ^ 1][rb * 64]);
      }
    }

    // S^T = K.Q^T: A=K (shared across tg), B=Q^T. D: S^T[s=nt*16+quad*4+r][t=l15]
    f32x4 S[2][4];
    #pragma unroll
    for (int nt = 0; nt < 4; nt++){
      const int rowb = (nt * 16 + l15) * 64;
      bf16x8 ak0 = *(const bf16x8*)&Ks[cur][rowb + ((quad ^ swf) * 8)];
      bf16x8 ak1 = *(const bf16x8*)&Ks[cur][rowb + (((4 + quad) ^ swf) * 8)];
      #pragma unroll
      for (int tg = 0; tg < 2; tg++){
        f32x4 a; a[0]=0.f; a[1]=0.f; a[2]=0.f; a[3]=0.f;
        a = __builtin_amdgcn_mfma_f32_16x16x32_bf16(ak0, bq[tg][0], a, 0, 0, 0);
        a = __builtin_amdgcn_mfma_f32_16x16x32_bf16(ak1, bq[tg][1], a, 0, 0, 0);
        S[tg][nt] = a;
      }
    }

    // bias + exp2. Saturation: all |s-t| >= 128 in tile -> constant bias (exact bucket clamp).
    const int drel = s0 - t0w;         // wave-uniform
    if (drel >= 160 || drel <= -192){
      const float sv = (drel > 0) ? tabh[1151] : tabh[895];   // rp=+128 / rp=-128 saturated values
      #pragma unroll
      for (int tg = 0; tg < 2; tg++){
        const float cb = g[tg] * sv;
        #pragma unroll
        for (int nt = 0; nt < 4; nt++)
          #pragma unroll
          for (int r = 0; r < 4; r++)
            S[tg][nt][r] = __builtin_amdgcn_exp2f(S[tg][nt][r] + cb);
      }
    } else {
      #pragma unroll
      for (int tg = 0; tg < 2; tg++){
        const int ib = ibase[tg] + s0;
        #pragma unroll
        for (int nt = 0; nt < 4; nt++)
          #pragma unroll
          for (int r = 0; r < 4; r++)
            S[tg][nt][r] = __builtin_amdgcn_exp2f(S[tg][nt][r] + g[tg] * tabh[ib + nt * 16 + quad * 4 + r]);
      }
    }

    // P^T -> wave-local LDS (t-major); denominator off critical path
    #pragma unroll
    for (int tg = 0; tg < 2; tg++){
      __bf16* pw = &Pt[wid][tg][0];
      #pragma unroll
      for (int nt = 0; nt < 4; nt++){
        bf16x4 p;
        p[0] = f2bf_fast(S[tg][nt][0]); p[1] = f2bf_fast(S[tg][nt][1]);
        p[2] = f2bf_fast(S[tg][nt][2]); p[3] = f2bf_fast(S[tg][nt][3]);
        *(bf16x4*)&pw[l15 * LDP + nt * 16 + quad * 4] = p;
      }
      float rs = 0.f;
      #pragma unroll
      for (int nt = 0; nt < 4; nt++) rs += (S[tg][nt][0] + S[tg][nt][1]) + (S[tg][nt][2] + S[tg][nt][3]);
      rs += __shfl_xor(rs, 16, 64);
      rs += __shfl_xor(rs, 32, 64);
      l_run[tg] += rs;
    }

    // O^T += V^T.P^T: A=V^T (shared across tg, swizzled), B=P^T
    #pragma unroll
    for (int ks = 0; ks < 2; ks++){
      bf16x8 bp[2];
      #pragma unroll
      for (int tg = 0; tg < 2; tg++)
        bp[tg] = *(const bf16x8*)&Pt[wid][tg][l15 * LDP + ks * 32 + quad * 8];
      #pragma unroll
      for (int mt = 0; mt < 4; mt++){
        const int rowb = (mt * 16 + l15) * 64;
        bf16x8 av = *(const bf16x8*)&Vt[cur][rowb + (((ks * 4 + quad) ^ swf) * 8)];
        #pragma unroll
        for (int tg = 0; tg < 2; tg++)
          O[tg][mt] = __builtin_amdgcn_mfma_f32_16x16x32_bf16(av, bp[tg], O[tg][mt], 0, 0, 0);
      }
    }

    __syncthreads();  // drains this wave's DMA (next tile staged) + all waves done reading buf[cur]
  }

  // epilogue: ctx[(t*B+b)*E + h*64+d], d = mt*16+quad*4+r
  #pragma unroll
  for (int tg = 0; tg < 2; tg++){
    const int t_lane = t0w + tg * 16 + l15;
    const float inv = 1.f / l_run[tg];
    #pragma unroll
    for (int mt = 0; mt < 4; mt++){
      bf16x4 o;
      o[0] = f2bf(O[tg][mt][0] * inv); o[1] = f2bf(O[tg][mt][1] * inv);
      o[2] = f2bf(O[tg][mt][2] * inv); o[3] = f2bf(O[tg][mt][3] * inv);
      *(bf16x4*)&ctx[(size_t)(t_lane * B_ + b) * E_ + h * DH_ + mt * 16 + quad * 4] = o;
    }
  }
}

extern "C" void kernel_launch(void* const* d_in, const int* in_sizes, int n_in,
                              void* d_out, int out_size, void* d_ws, size_t ws_size,
                              hipStream_t stream)
{
  (void)in_sizes; (void)n_in; (void)out_size; (void)ws_size;
  const float* query    = (const float*)d_in[0];
  const float* q_w      = (const float*)d_in[1];
  const float* q_b      = (const float*)d_in[2];
  const float* k_w      = (const float*)d_in[3];
  const float* k_b      = (const float*)d_in[4];
  const float* v_w      = (const float*)d_in[5];
  const float* v_b      = (const float*)d_in[6];
  const float* out_w    = (const float*)d_in[7];
  const float* out_b    = (const float*)d_in[8];
  const float* rel_bias = (const float*)d_in[9];
  const float* grep_w   = (const float*)d_in[10];
  const float* grep_b   = (const float*)d_in[11];
  const float* grep_a   = (const float*)d_in[12];

  char* ws = (char*)d_ws;
  size_t off = 0;
  __bf16* qbf = (__bf16*)(ws + off); off += (size_t)4096 * 1024 * 2;   // query bf16 (TB, E)
  __bf16* wq  = (__bf16*)(ws + off); off += (size_t)1024 * 1024 * 2;
  __bf16* wk  = (__bf16*)(ws + off); off += (size_t)1024 * 1024 * 2;
  __bf16* wv  = (__bf16*)(ws + off); off += (size_t)1024 * 1024 * 2;
  __bf16* wo  = (__bf16*)(ws + off); off += (size_t)1024 * 1024 * 2;
  __bf16* qh  = (__bf16*)(ws + off); off += (size_t)4096 * 1024 * 2;   // (B,H,T,DH)
  __bf16* kh  = (__bf16*)(ws + off); off += (size_t)4096 * 1024 * 2;   // (B,H,T,DH)
  __bf16* vhT = (__bf16*)(ws + off); off += (size_t)4096 * 1024 * 2;   // (B,H,DH,T)
  __bf16* ctx = (__bf16*)(ws + off); off += (size_t)4096 * 1024 * 2;   // (TB, E)
  float* gates = (float*)(ws + off); off += (size_t)65536 * 4;         // (B*H, T), * log2e
  float* tab   = (float*)(ws + off); off += (size_t)16 * 2047 * 4;     // (H, 2047) fp32

  prep_kernel<<<4480, 256, 0, stream>>>(q_w, k_w, v_w, out_w, wq, wk, wv, wo,
                                        query, grep_w, grep_b, grep_a, gates, qbf,
                                        rel_bias, tab);
  gemm_qkv<<<192, 512, 0, stream>>>(qbf, wq, wk, wv, q_b, k_b, v_b, qh, kh, vhT);
  attn_kernel<<<512, 256, 0, stream>>>(qh, kh, vhT, gates, tab, ctx);
  gemm_out<<<512, 256, 0, stream>>>(ctx, wo, out_b, (float*)d_out);
}

// Round 7
// 208.802 us; speedup vs baseline: 1.0295x; 1.0295x over previous
//
#include <hip/hip_runtime.h>
#include <math.h>

// Problem constants (reference: T,B,E,H = 1024,4,1024,16; DH=64; 32 buckets, max_dist 128)
#define T_ 1024
#define B_ 4
#define E_ 1024
#define H_ 16
#define DH_ 64

#define LOG2E 1.44269504088896f

typedef __attribute__((ext_vector_type(8))) __bf16 bf16x8;
typedef __attribute__((ext_vector_type(4))) __bf16 bf16x4;
typedef __attribute__((ext_vector_type(4))) float f32x4;

// fp32 -> bf16 round-to-nearest-even
__device__ __forceinline__ __bf16 f2bf(float x){
  union { unsigned short u; __bf16 b; } cv;
  unsigned u32 = __float_as_uint(x);
  cv.u = (unsigned short)((u32 + 0x7fffu + ((u32 >> 16) & 1u)) >> 16);
  return cv.b;
}
// fp32 -> bf16 round-half-up (cheaper; used only for P >= 0)
__device__ __forceinline__ __bf16 f2bf_fast(float x){
  union { unsigned short u; __bf16 b; } cv;
  cv.u = (unsigned short)((__float_as_uint(x) + 0x8000u) >> 16);
  return cv.b;
}

// async global->LDS, 16B per lane; LDS dest is wave-uniform base + lane*16 (m97/m104)
__device__ __forceinline__ void glds16(const void* g, void* l){
  __builtin_amdgcn_global_load_lds(
      (__attribute__((address_space(1))) void*)(void*)g,
      (__attribute__((address_space(3))) void*)l,
      16, 0, 0);
}

#define PBAR() do { asm volatile("" ::: "memory"); __builtin_amdgcn_s_barrier(); asm volatile("" ::: "memory"); } while(0)
#define VDRAIN() asm volatile("s_waitcnt vmcnt(0)" ::: "memory")

// ---------------- prep: weight cvt (blocks 0..4095) + gates/qbf (4096..4351) + tab (4352..4479) ----------------
__global__ __launch_bounds__(256) void prep_kernel(
    const float* __restrict__ q_w, const float* __restrict__ k_w,
    const float* __restrict__ v_w, const float* __restrict__ out_w,
    __bf16* __restrict__ wq, __bf16* __restrict__ wk,
    __bf16* __restrict__ wv, __bf16* __restrict__ wo,
    const float* __restrict__ query, const float* __restrict__ gw,
    const float* __restrict__ gb, const float* __restrict__ ga,
    float* __restrict__ gates, __bf16* __restrict__ qbf,
    const float* __restrict__ rel_bias, float* __restrict__ tab)
{
  const int bid = blockIdx.x;
  const int tid = threadIdx.x;
  if (bid < 4096){
    const float* a; __bf16* o;
    switch (bid >> 10){
      case 0: a = q_w;  o = wq; break;
      case 1: a = k_w;  o = wk; break;
      case 2: a = v_w;  o = wv; break;
      default: a = out_w; o = wo; break;
    }
    int i = ((bid & 1023) * 256 + tid) * 4;
    float4 v = *(const float4*)(a + i);
    bf16x4 r;
    r[0] = f2bf(v.x); r[1] = f2bf(v.y); r[2] = f2bf(v.z); r[3] = f2bf(v.w);
    *(bf16x4*)(o + i) = r;
  } else if (bid < 4352){
    int t = (bid - 4096) * 4 + (tid >> 6);
    int bh = tid & 63;
    int h = bh & 15;
    const float* q = query + (size_t)t * E_ * B_ + bh * 64;
    __bf16* qo = qbf + (size_t)t * E_ * B_ + bh * 64;
    float g[8];
    #pragma unroll
    for (int e = 0; e < 8; e++) g[e] = gb[e];
    #pragma unroll
    for (int c = 0; c < 8; c++){
      float4 v0 = *(const float4*)(q + c * 8);
      float4 v1 = *(const float4*)(q + c * 8 + 4);
      bf16x8 o;
      o[0] = f2bf(v0.x); o[1] = f2bf(v0.y); o[2] = f2bf(v0.z); o[3] = f2bf(v0.w);
      o[4] = f2bf(v1.x); o[5] = f2bf(v1.y); o[6] = f2bf(v1.z); o[7] = f2bf(v1.w);
      *(bf16x8*)(qo + c * 8) = o;
      #pragma unroll
      for (int e = 0; e < 8; e++){
        const float* w = gw + e * 64 + c * 8;     // uniform -> s_load
        g[e] += v0.x * w[0] + v0.y * w[1] + v0.z * w[2] + v0.w * w[3]
              + v1.x * w[4] + v1.y * w[5] + v1.z * w[6] + v1.w * w[7];
      }
    }
    float a0 = (g[0] + g[1]) + (g[2] + g[3]);
    float a1 = (g[4] + g[5]) + (g[6] + g[7]);
    float sa = 1.f / (1.f + __expf(-a0));
    float sb = 1.f / (1.f + __expf(-a1));
    gates[bh * T_ + t] = (sa * (sb * ga[h] - 1.0f) + 2.0f) * LOG2E;   // pre-scaled for exp2
  } else {
    int tb = bid - 4352;               // 0..127
    int h = tb >> 3;
    int i = (tb & 7) * 256 + tid;
    if (i < 2047){
      int rp = i - 1023;
      int base = rp > 0 ? 16 : 0;
      int arp = rp < 0 ? -rp : rp;
      int off;
      if (arp < 8) off = arp;
      else {
        float val = (logf((float)arp * 0.125f) / 2.772588722239781f) * 8.0f;
        int lg = (int)val;
        off = 8 + (lg > 7 ? 7 : lg);
      }
      tab[h * 2047 + i] = rel_bias[(base + off) * H_ + h];   // fp32 now
    }
  }
}

// ---------------- fused QKV GEMM v6: 4096 x 3072 x 1024, 256m x 192n tile, grid 256 (exact CU fill) ----------------
// B = [Wq|Wk|Wv] flat (contiguous in workspace). 8 waves (2m x 4n), per-wave 128 x 48, BK=64.
// Per K-tile: 4 phases {ds_read subtile | barrier | setprio + 12 MFMA | barrier}; ALL 7 next-tile
// stages issued in P0 (A, 4) and P1 (B, 3) so the last stage has ~2.5 phases of cover before the
// end-of-tile drain (T4 mechanism: loads in flight across barriers). LDS 112 KB dbuf, 1 block/CU.
// Per-element accumulation order (kq0 then kq1 per K-tile) identical to prior rounds.
__global__ __launch_bounds__(512, 1) void gemm_qkv(
    const __bf16* __restrict__ A, const __bf16* __restrict__ W,
    const float* __restrict__ b0, const float* __restrict__ b1, const float* __restrict__ b2,
    __bf16* out0, __bf16* out1, __bf16* out2)
{
  __shared__ __bf16 smem[57344];       // 112 KB: As[2][256*64] | Bs[2][192*64]; reused as vbuf
  const int tid = threadIdx.x;
  const int lane = tid & 63, wid = tid >> 6;   // 8 waves
  const int l15 = lane & 15, quad = lane >> 4;
  const int wr = wid >> 2, wc = wid & 3;       // wave grid 2m x 4n
  const int dd = blockIdx.x;                   // 0..255
  const int j = dd >> 3;                       // 0..31
  const int bm = (dd & 7) * 2 + (j & 1);       // 0..15, m fast within XCD -> A-slab L2 reuse
  const int bn = j >> 1;                       // 0..15
  const int m0 = bm * 256;
  const int n0 = bn * 192;                     // flat col base in [0,3072)

  const int grow = lane >> 3;
  const int gcol = (((lane & 7) ^ grow) * 8);  // XOR-swizzled source chunk
  const int sw = (l15 & 7);                    // frag-read swizzle key

  f32x4 acc[8][3];
  #pragma unroll
  for (int i = 0; i < 8; i++)
    #pragma unroll
    for (int jj = 0; jj < 3; jj++){
      acc[i][jj][0] = 0.f; acc[i][jj][1] = 0.f; acc[i][jj][2] = 0.f; acc[i][jj][3] = 0.f;
    }

  auto SA = [&](int nb, int kn, int r){        // stage 8 A-rows (wave-uniform dest)
    const int rb = wid * 32 + r * 8;           // 8 waves x 4 = 256 rows
    glds16(A + (size_t)(m0 + rb + grow) * E_ + kn + gcol, smem + nb * 16384 + rb * 64);
  };
  auto SB = [&](int nb, int kn, int r){        // stage 8 B-rows (flat col = row index)
    const int rb = wid * 24 + r * 8;           // 8 waves x 3 = 192 rows
    glds16(W + (size_t)(n0 + rb + grow) * E_ + kn + gcol, smem + 32768 + nb * 12288 + rb * 64);
  };

  bf16x8 am[4], bnr[3];
  auto RDA = [&](const __bf16* Ac, int mh, int kq){
    const int ce = ((kq * 4 + quad) ^ sw) * 8;
    #pragma unroll
    for (int i = 0; i < 4; i++)
      am[i] = *(const bf16x8*)&Ac[(wr * 128 + mh * 64 + i * 16 + l15) * 64 + ce];
  };
  auto RDB = [&](const __bf16* Bc, int kq){
    const int ce = ((kq * 4 + quad) ^ sw) * 8;
    #pragma unroll
    for (int jj = 0; jj < 3; jj++)
      bnr[jj] = *(const bf16x8*)&Bc[(wc * 48 + jj * 16 + l15) * 64 + ce];
  };
  auto MM = [&](int mh){
    __builtin_amdgcn_s_setprio(1);
    #pragma unroll
    for (int i = 0; i < 4; i++)
      #pragma unroll
      for (int jj = 0; jj < 3; jj++)
        acc[mh * 4 + i][jj] = __builtin_amdgcn_mfma_f32_16x16x32_bf16(am[i], bnr[jj], acc[mh * 4 + i][jj], 0, 0, 0);
    __builtin_amdgcn_s_setprio(0);
  };

  // prologue: stage K-tile 0 into buf 0, full drain
  #pragma unroll
  for (int r = 0; r < 4; r++) SA(0, 0, r);
  #pragma unroll
  for (int r = 0; r < 3; r++) SB(0, 0, r);
  VDRAIN();
  PBAR();

  for (int t = 0; t < 16; t++){
    const __bf16* Ac = smem + (t & 1) * 16384;
    const __bf16* Bc = smem + 32768 + (t & 1) * 12288;
    const int nb = (t & 1) ^ 1;
    const int kn = (t + 1) * 64;
    const bool pf = (t < 15);
    // P0: mh0/kq0; stage ALL next-tile A (4 issues) -> max cover
    RDA(Ac, 0, 0); RDB(Bc, 0);
    if (pf){ SA(nb, kn, 0); SA(nb, kn, 1); SA(nb, kn, 2); SA(nb, kn, 3); }
    PBAR();
    MM(0);
    PBAR();
    // P1: mh1/kq0 (bnr reused); stage ALL next-tile B (3 issues)
    RDA(Ac, 1, 0);
    if (pf){ SB(nb, kn, 0); SB(nb, kn, 1); SB(nb, kn, 2); }
    PBAR();
    MM(1);
    PBAR();
    // P2: mh0/kq1
    RDA(Ac, 0, 1); RDB(Bc, 1);
    PBAR();
    MM(0);
    PBAR();
    // P3: mh1/kq1; drain (stages have had >=2.5 phases of cover)
    RDA(Ac, 1, 1);
    PBAR();
    MM(1);
    if (pf) VDRAIN();
    PBAR();
  }

  // q/k epilogue (per-fragment z): out[((bb*H + nt)*T + t)*DH + d2]
  const int cb0 = wc * 48;
  #pragma unroll
  for (int nf = 0; nf < 3; nf++){
    const int colb = n0 + cb0 + nf * 16;       // flat col base, mult of 16
    const int z = colb >> 10;
    if (z < 2){
      __bf16* outp = z ? out1 : out0;
      const float scale = z ? 1.0f : 0.125f * LOG2E;
      const int nt = (colb >> 6) & 15;
      const int d2 = (colb & 63) + l15;
      const float bc = (z ? b1 : b0)[nt * 64 + d2];
      #pragma unroll
      for (int mf = 0; mf < 8; mf++){
        const int tb = (m0 + wr * 128 + mf * 16 + quad * 4) >> 2;   // base%4==0 -> bb = r
        #pragma unroll
        for (int r = 0; r < 4; r++){
          float v = (acc[mf][nf][r] + bc) * scale;
          outp[(size_t)((r * H_ + nt) * T_ + tb) * DH_ + d2] = f2bf(v);
        }
      }
    }
  }

  // v epilogue: transpose via LDS (smem reuse as vbuf[192][4][64] = 96 KB)
  __bf16 (*vbuf)[4][64] = (__bf16 (*)[4][64])smem;
  #pragma unroll
  for (int nf = 0; nf < 3; nf++){
    const int colb = n0 + cb0 + nf * 16;
    if (colb >= 2048){
      const int c = cb0 + nf * 16 + l15;       // local col 0..191
      const float bc = b2[(colb & 1023) + l15];
      #pragma unroll
      for (int mf = 0; mf < 8; mf++){
        const int tl = wr * 32 + mf * 4 + quad;  // local t 0..63
        #pragma unroll
        for (int r = 0; r < 4; r++)
          vbuf[c][r][tl] = f2bf(acc[mf][nf][r] + bc);
      }
    }
  }
  PBAR();
  for (int jb = tid; jb < 768; jb += 512){     // (col, bb) jobs
    const int c = jb >> 2, bb = jb & 3;
    const int col = n0 + c;
    if (col >= 2048){
      const int cv = col & 1023;
      const int nt = cv >> 6, dl = cv & 63;
      __bf16* dst = out2 + (size_t)((bb * H_ + nt) * DH_ + dl) * T_ + (m0 >> 2);
      const __bf16* src = &vbuf[c][bb][0];
      #pragma unroll
      for (int cc = 0; cc < 8; cc++)
        *(bf16x8*)(dst + cc * 8) = *(const bf16x8*)(src + cc * 8);
    }
  }
}

// ---------------- out-proj GEMM: 64x128 tile, BK=64, XOR-swizzled LDS, XCD grid (512), fp32 write ----------------
__global__ __launch_bounds__(256) void gemm_out(
    const __bf16* __restrict__ A, const __bf16* __restrict__ W,
    const float* __restrict__ bias, float* __restrict__ out)
{
  __shared__ __bf16 As[64 * 64];
  __shared__ __bf16 Bs[128 * 64];
  const int tid = threadIdx.x;
  const int lane = tid & 63, wid = tid >> 6;
  const int l15 = lane & 15, quad = lane >> 4;
  const int wm = wid >> 1, wn = wid & 1;
  const int dd = blockIdx.x;
  const int j = dd >> 3;
  const int m0 = ((dd & 7) * 8 + (j & 7)) * 64;
  const int n0 = (j >> 3) * 128;

  f32x4 acc[2][4];
  #pragma unroll
  for (int i = 0; i < 2; i++)
    #pragma unroll
    for (int jj = 0; jj < 4; jj++){
      acc[i][jj][0] = 0.f; acc[i][jj][1] = 0.f; acc[i][jj][2] = 0.f; acc[i][jj][3] = 0.f;
    }

  const int grow = lane >> 3;
  const int gcol = (((lane & 7) ^ grow) * 8);
  const int sw = (l15 & 7);

  for (int k0 = 0; k0 < E_; k0 += 64){
    __syncthreads();
    #pragma unroll
    for (int r = 0; r < 2; r++){
      int rbA = wid * 16 + r * 8;
      glds16(A + (size_t)(m0 + rbA + grow) * E_ + k0 + gcol, &As[rbA * 64]);
    }
    #pragma unroll
    for (int r = 0; r < 4; r++){
      int rbB = wid * 32 + r * 8;
      glds16(W + (size_t)(n0 + rbB + grow) * E_ + k0 + gcol, &Bs[rbB * 64]);
    }
    __syncthreads();
    #pragma unroll
    for (int kq = 0; kq < 2; kq++){
      const int ce = ((kq * 4 + quad) ^ sw) * 8;
      bf16x8 am[2], bn[4];
      #pragma unroll
      for (int i = 0; i < 2; i++) am[i] = *(const bf16x8*)&As[(wm * 32 + i * 16 + l15) * 64 + ce];
      #pragma unroll
      for (int jj = 0; jj < 4; jj++) bn[jj] = *(const bf16x8*)&Bs[(wn * 64 + jj * 16 + l15) * 64 + ce];
      #pragma unroll
      for (int i = 0; i < 2; i++)
        #pragma unroll
        for (int jj = 0; jj < 4; jj++)
          acc[i][jj] = __builtin_amdgcn_mfma_f32_16x16x32_bf16(am[i], bn[jj], acc[i][jj], 0, 0, 0);
    }
  }

  #pragma unroll
  for (int i = 0; i < 2; i++){
    const int row0 = m0 + wm * 32 + i * 16 + quad * 4;
    #pragma unroll
    for (int jj = 0; jj < 4; jj++){
      const int col = n0 + wn * 64 + jj * 16 + l15;
      const float bc = bias[col];
      #pragma unroll
      for (int r = 0; r < 4; r++)
        out[(size_t)(row0 + r) * E_ + col] = acc[i][jj][r] + bc;
    }
  }
}

// ---------------- flash attention v6: 128 t per block, 256 thr (4 waves), 2 blocks/CU ----------------
// Double-buffered K/V DMA (depth-1 pipeline); ONE __syncthreads per tile.
__global__ __launch_bounds__(256) void attn_kernel(
    const __bf16* __restrict__ qg, const __bf16* __restrict__ kg, const __bf16* __restrict__ vgT,
    const float* __restrict__ gates, const float* __restrict__ tab,
    __bf16* __restrict__ ctx)
{
  const int LDP = 72;                  // P rows padded (written by VALU, b64/b128 path)
  __shared__ __bf16 Ks[2][64 * 64];    // 2 x 8 KB, swizzled chunks: slot c holds global chunk c^(row&7)
  __shared__ __bf16 Vt[2][64 * 64];    // 2 x 8 KB, swizzled (rows = d, cols = s)
  __shared__ __bf16 Pt[4][2][16 * LDP];// per-(wave, tg) P^T
  __shared__ float tabh[2048];         // fp32 rel-bias row for this h

  const int tid = threadIdx.x;
  const int lane = tid & 63, wid = tid >> 6;       // 4 waves
  const int l15 = lane & 15, quad = lane >> 4;
  // XCD swizzle: all 8 t-blocks of a bh share XCD slot d&7
  const int dgrid = blockIdx.x;
  const int j = dgrid >> 3;
  const int bh = (dgrid & 7) + 8 * (j & 7);
  const int tq = j >> 3;               // 0..7 -> t-base tq*128
  const int b = bh >> 4, h = bh & 15;
  const __bf16* qb = qg + (size_t)bh * T_ * DH_;
  const __bf16* kb = kg + (size_t)bh * T_ * DH_;
  const __bf16* vb = vgT + (size_t)bh * DH_ * T_;

  for (int i = tid; i < 2047; i += 256) tabh[i] = tab[h * 2047 + i];

  const int t0w = tq * 128 + wid * 32; // wave owns 32 t = 2 groups of 16
  bf16x8 bq[2][2];
  float g[2];
  int ibase[2];
  #pragma unroll
  for (int tg = 0; tg < 2; tg++){
    int t_lane = t0w + tg * 16 + l15;
    bq[tg][0] = *(const bf16x8*)(qb + (size_t)t_lane * DH_ + quad * 8);
    bq[tg][1] = *(const bf16x8*)(qb + (size_t)t_lane * DH_ + 32 + quad * 8);
    g[tg] = gates[bh * T_ + t_lane];   // already * log2e
    ibase[tg] = 1023 - t_lane;
  }

  const int grow = lane >> 3;                  // staging row within 8-row group
  const int gcol = (((lane & 7) ^ grow) * 8);  // XOR-swizzled source chunk
  const int swf = (l15 & 7);                   // frag-read swizzle key

  float l_run[2] = {0.f, 0.f};
  f32x4 O[2][4];
  #pragma unroll
  for (int tg = 0; tg < 2; tg++)
    #pragma unroll
    for (int mt = 0; mt < 4; mt++){ O[tg][mt][0]=0.f; O[tg][mt][1]=0.f; O[tg][mt][2]=0.f; O[tg][mt][3]=0.f; }

  // prologue: stage s-tile 0 into buffer 0 (wave stages rows [wid*16, wid*16+16))
  #pragma unroll
  for (int r = 0; r < 2; r++){
    int rb = wid * 16 + r * 8;
    glds16(kb + (size_t)(rb + grow) * DH_ + gcol, &Ks[0][rb * 64]);
    glds16(vb + (size_t)(rb + grow) * T_ + gcol, &Vt[0][rb * 64]);
  }
  __syncthreads();                     // implicit vmcnt(0): tile 0 staged

  for (int it = 0; it < 16; it++){
    const int s0 = it * 64;
    const int cur = it & 1;

    // issue next tile's DMA into the other buffer (overlaps with compute below)
    if (it < 15){
      const int sn = s0 + 64;
      #pragma unroll
      for (int r = 0; r < 2; r++){
        int rb = wid * 16 + r * 8;
        glds16(kb + (size_t)(sn + rb + grow) * DH_ + gcol, &Ks[cur ^ 1][rb * 64]);
        glds16(vb + (size_t)(rb + grow) * T_ + sn + gcol, &Vt[cur ^ 1][rb * 64]);
      }
    }

    // S^T = K.Q^T: A=K (shared across tg), B=Q^T. D: S^T[s=nt*16+quad*4+r][t=l15]
    f32x4 S[2][4];
    #pragma unroll
    for (int nt = 0; nt < 4; nt++){
      const int rowb = (nt * 16 + l15) * 64;
      bf16x8 ak0 = *(const bf16x8*)&Ks[cur][rowb + ((quad ^ swf) * 8)];
      bf16x8 ak1 = *(const bf16x8*)&Ks[cur][rowb + (((4 + quad) ^ swf) * 8)];
      #pragma unroll
      for (int tg = 0; tg < 2; tg++){
        f32x4 a; a[0]=0.f; a[1]=0.f; a[2]=0.f; a[3]=0.f;
        a = __builtin_amdgcn_mfma_f32_16x16x32_bf16(ak0, bq[tg][0], a, 0, 0, 0);
        a = __builtin_amdgcn_mfma_f32_16x16x32_bf16(ak1, bq[tg][1], a, 0, 0, 0);
        S[tg][nt] = a;
      }
    }

    // bias + exp2. Saturation: all |s-t| >= 128 in tile -> constant bias (exact bucket clamp).
    const int drel = s0 - t0w;         // wave-uniform
    if (drel >= 160 || drel <= -192){
      const float sv = (drel > 0) ? tabh[1151] : tabh[895];   // rp=+128 / rp=-128 saturated values
      #pragma unroll
      for (int tg = 0; tg < 2; tg++){
        const float cb = g[tg] * sv;
        #pragma unroll
        for (int nt = 0; nt < 4; nt++)
          #pragma unroll
          for (int r = 0; r < 4; r++)
            S[tg][nt][r] = __builtin_amdgcn_exp2f(S[tg][nt][r] + cb);
      }
    } else {
      #pragma unroll
      for (int tg = 0; tg < 2; tg++){
        const int ib = ibase[tg] + s0;
        #pragma unroll
        for (int nt = 0; nt < 4; nt++)
          #pragma unroll
          for (int r = 0; r < 4; r++)
            S[tg][nt][r] = __builtin_amdgcn_exp2f(S[tg][nt][r] + g[tg] * tabh[ib + nt * 16 + quad * 4 + r]);
      }
    }

    // P^T -> wave-local LDS (t-major); denominator off critical path
    #pragma unroll
    for (int tg = 0; tg < 2; tg++){
      __bf16* pw = &Pt[wid][tg][0];
      #pragma unroll
      for (int nt = 0; nt < 4; nt++){
        bf16x4 p;
        p[0] = f2bf_fast(S[tg][nt][0]); p[1] = f2bf_fast(S[tg][nt][1]);
        p[2] = f2bf_fast(S[tg][nt][2]); p[3] = f2bf_fast(S[tg][nt][3]);
        *(bf16x4*)&pw[l15 * LDP + nt * 16 + quad * 4] = p;
      }
      float rs = 0.f;
      #pragma unroll
      for (int nt = 0; nt < 4; nt++) rs += (S[tg][nt][0] + S[tg][nt][1]) + (S[tg][nt][2] + S[tg][nt][3]);
      rs += __shfl_xor(rs, 16, 64);
      rs += __shfl_xor(rs, 32, 64);
      l_run[tg] += rs;
    }

    // O^T += V^T.P^T: A=V^T (shared across tg, swizzled), B=P^T
    #pragma unroll
    for (int ks = 0; ks < 2; ks++){
      bf16x8 bp[2];
      #pragma unroll
      for (int tg = 0; tg < 2; tg++)
        bp[tg] = *(const bf16x8*)&Pt[wid][tg][l15 * LDP + ks * 32 + quad * 8];
      #pragma unroll
      for (int mt = 0; mt < 4; mt++){
        const int rowb = (mt * 16 + l15) * 64;
        bf16x8 av = *(const bf16x8*)&Vt[cur][rowb + (((ks * 4 + quad) ^ swf) * 8)];
        #pragma unroll
        for (int tg = 0; tg < 2; tg++)
          O[tg][mt] = __builtin_amdgcn_mfma_f32_16x16x32_bf16(av, bp[tg], O[tg][mt], 0, 0, 0);
      }
    }

    __syncthreads();  // drains this wave's DMA (next tile staged) + all waves done reading buf[cur]
  }

  // epilogue: ctx[(t*B+b)*E + h*64+d], d = mt*16+quad*4+r
  #pragma unroll
  for (int tg = 0; tg < 2; tg++){
    const int t_lane = t0w + tg * 16 + l15;
    const float inv = 1.f / l_run[tg];
    #pragma unroll
    for (int mt = 0; mt < 4; mt++){
      bf16x4 o;
      o[0] = f2bf(O[tg][mt][0] * inv); o[1] = f2bf(O[tg][mt][1] * inv);
      o[2] = f2bf(O[tg][mt][2] * inv); o[3] = f2bf(O[tg][mt][3] * inv);
      *(bf16x4*)&ctx[(size_t)(t_lane * B_ + b) * E_ + h * DH_ + mt * 16 + quad * 4] = o;
    }
  }
}

extern "C" void kernel_launch(void* const* d_in, const int* in_sizes, int n_in,
                              void* d_out, int out_size, void* d_ws, size_t ws_size,
                              hipStream_t stream)
{
  (void)in_sizes; (void)n_in; (void)out_size; (void)ws_size;
  const float* query    = (const float*)d_in[0];
  const float* q_w      = (const float*)d_in[1];
  const float* q_b      = (const float*)d_in[2];
  const float* k_w      = (const float*)d_in[3];
  const float* k_b      = (const float*)d_in[4];
  const float* v_w      = (const float*)d_in[5];
  const float* v_b      = (const float*)d_in[6];
  const float* out_w    = (const float*)d_in[7];
  const float* out_b    = (const float*)d_in[8];
  const float* rel_bias = (const float*)d_in[9];
  const float* grep_w   = (const float*)d_in[10];
  const float* grep_b   = (const float*)d_in[11];
  const float* grep_a   = (const float*)d_in[12];

  char* ws = (char*)d_ws;
  size_t off = 0;
  __bf16* qbf = (__bf16*)(ws + off); off += (size_t)4096 * 1024 * 2;   // query bf16 (TB, E)
  __bf16* wq  = (__bf16*)(ws + off); off += (size_t)1024 * 1024 * 2;   // NOTE: wq,wk,wv contiguous
  __bf16* wk  = (__bf16*)(ws + off); off += (size_t)1024 * 1024 * 2;   //  -> flat [3072][1024] B
  __bf16* wv  = (__bf16*)(ws + off); off += (size_t)1024 * 1024 * 2;
  __bf16* wo  = (__bf16*)(ws + off); off += (size_t)1024 * 1024 * 2;
  __bf16* qh  = (__bf16*)(ws + off); off += (size_t)4096 * 1024 * 2;   // (B,H,T,DH)
  __bf16* kh  = (__bf16*)(ws + off); off += (size_t)4096 * 1024 * 2;   // (B,H,T,DH)
  __bf16* vhT = (__bf16*)(ws + off); off += (size_t)4096 * 1024 * 2;   // (B,H,DH,T)
  __bf16* ctx = (__bf16*)(ws + off); off += (size_t)4096 * 1024 * 2;   // (TB, E)
  float* gates = (float*)(ws + off); off += (size_t)65536 * 4;         // (B*H, T), * log2e
  float* tab   = (float*)(ws + off); off += (size_t)16 * 2047 * 4;     // (H, 2047) fp32

  prep_kernel<<<4480, 256, 0, stream>>>(q_w, k_w, v_w, out_w, wq, wk, wv, wo,
                                        query, grep_w, grep_b, grep_a, gates, qbf,
                                        rel_bias, tab);
  gemm_qkv<<<256, 512, 0, stream>>>(qbf, wq, q_b, k_b, v_b, qh, kh, vhT);
  attn_kernel<<<512, 256, 0, stream>>>(qh, kh, vhT, gates, tab, ctx);
  gemm_out<<<512, 256, 0, stream>>>(ctx, wo, out_b, (float*)d_out);
}

// Round 8
// 195.688 us; speedup vs baseline: 1.0985x; 1.0670x over previous
//
#include <hip/hip_runtime.h>
#include <math.h>

// Problem constants (reference: T,B,E,H = 1024,4,1024,16; DH=64; 32 buckets, max_dist 128)
#define T_ 1024
#define B_ 4
#define E_ 1024
#define H_ 16
#define DH_ 64

#define LOG2E 1.44269504088896f

typedef __attribute__((ext_vector_type(8))) __bf16 bf16x8;
typedef __attribute__((ext_vector_type(4))) __bf16 bf16x4;
typedef __attribute__((ext_vector_type(4))) float f32x4;

// fp32 -> bf16 round-to-nearest-even
__device__ __forceinline__ __bf16 f2bf(float x){
  union { unsigned short u; __bf16 b; } cv;
  unsigned u32 = __float_as_uint(x);
  cv.u = (unsigned short)((u32 + 0x7fffu + ((u32 >> 16) & 1u)) >> 16);
  return cv.b;
}
// fp32 -> bf16 round-half-up (cheaper; used only for P >= 0)
__device__ __forceinline__ __bf16 f2bf_fast(float x){
  union { unsigned short u; __bf16 b; } cv;
  cv.u = (unsigned short)((__float_as_uint(x) + 0x8000u) >> 16);
  return cv.b;
}

// async global->LDS, 16B per lane; LDS dest is wave-uniform base + lane*16 (m97/m104)
__device__ __forceinline__ void glds16(const void* g, void* l){
  __builtin_amdgcn_global_load_lds(
      (__attribute__((address_space(1))) void*)(void*)g,
      (__attribute__((address_space(3))) void*)l,
      16, 0, 0);
}

// ---------------- prep: weight cvt (blocks 0..4095) + gates/qbf (4096..4351) + tab (4352..4479) ----------------
__global__ __launch_bounds__(256) void prep_kernel(
    const float* __restrict__ q_w, const float* __restrict__ k_w,
    const float* __restrict__ v_w, const float* __restrict__ out_w,
    __bf16* __restrict__ wq, __bf16* __restrict__ wk,
    __bf16* __restrict__ wv, __bf16* __restrict__ wo,
    const float* __restrict__ query, const float* __restrict__ gw,
    const float* __restrict__ gb, const float* __restrict__ ga,
    float* __restrict__ gates, __bf16* __restrict__ qbf,
    const float* __restrict__ rel_bias, float* __restrict__ tab)
{
  const int bid = blockIdx.x;
  const int tid = threadIdx.x;
  if (bid < 4096){
    const float* a; __bf16* o;
    switch (bid >> 10){
      case 0: a = q_w;  o = wq; break;
      case 1: a = k_w;  o = wk; break;
      case 2: a = v_w;  o = wv; break;
      default: a = out_w; o = wo; break;
    }
    int i = ((bid & 1023) * 256 + tid) * 4;
    float4 v = *(const float4*)(a + i);
    bf16x4 r;
    r[0] = f2bf(v.x); r[1] = f2bf(v.y); r[2] = f2bf(v.z); r[3] = f2bf(v.w);
    *(bf16x4*)(o + i) = r;
  } else if (bid < 4352){
    int t = (bid - 4096) * 4 + (tid >> 6);
    int bh = tid & 63;
    int h = bh & 15;
    const float* q = query + (size_t)t * E_ * B_ + bh * 64;
    __bf16* qo = qbf + (size_t)t * E_ * B_ + bh * 64;
    float g[8];
    #pragma unroll
    for (int e = 0; e < 8; e++) g[e] = gb[e];
    #pragma unroll
    for (int c = 0; c < 8; c++){
      float4 v0 = *(const float4*)(q + c * 8);
      float4 v1 = *(const float4*)(q + c * 8 + 4);
      bf16x8 o;
      o[0] = f2bf(v0.x); o[1] = f2bf(v0.y); o[2] = f2bf(v0.z); o[3] = f2bf(v0.w);
      o[4] = f2bf(v1.x); o[5] = f2bf(v1.y); o[6] = f2bf(v1.z); o[7] = f2bf(v1.w);
      *(bf16x8*)(qo + c * 8) = o;
      #pragma unroll
      for (int e = 0; e < 8; e++){
        const float* w = gw + e * 64 + c * 8;     // uniform -> s_load
        g[e] += v0.x * w[0] + v0.y * w[1] + v0.z * w[2] + v0.w * w[3]
              + v1.x * w[4] + v1.y * w[5] + v1.z * w[6] + v1.w * w[7];
      }
    }
    float a0 = (g[0] + g[1]) + (g[2] + g[3]);
    float a1 = (g[4] + g[5]) + (g[6] + g[7]);
    float sa = 1.f / (1.f + __expf(-a0));
    float sb = 1.f / (1.f + __expf(-a1));
    gates[bh * T_ + t] = (sa * (sb * ga[h] - 1.0f) + 2.0f) * LOG2E;   // pre-scaled for exp2
  } else {
    int tb = bid - 4352;               // 0..127
    int h = tb >> 3;
    int i = (tb & 7) * 256 + tid;
    if (i < 2047){
      int rp = i - 1023;
      int base = rp > 0 ? 16 : 0;
      int arp = rp < 0 ? -rp : rp;
      int off;
      if (arp < 8) off = arp;
      else {
        float val = (logf((float)arp * 0.125f) / 2.772588722239781f) * 8.0f;
        int lg = (int)val;
        off = 8 + (lg > 7 ? 7 : lg);
      }
      tab[h * 2047 + i] = rel_bias[(base + off) * H_ + h];   // fp32 now
    }
  }
}

// ---------------- fused QKV GEMM (round-0 2-phase, best measured): 128m x 64n x {q,k,v} ----------------
// v-epilogue vbuf now XOR-swizzled: elem (nl,bb,tloc) at byte (nl*256 + bb*64 + tloc*2) ^ ((nl&7)<<4).
// Old linear layout had nl-stride 256B = 0 mod bank-cycle -> 16-way conflicts on both the scalar
// transpose-writes and the b128 copy-out reads (~2.1M conflict cycles/dispatch, round-3 probe).
// XOR spreads the 16 l15 lanes over 8 16B slots -> 2-way (free). Same values, relocated slots only.
__global__ __launch_bounds__(256, 2) void gemm_qkv(
    const __bf16* __restrict__ A,
    const __bf16* __restrict__ W0, const __bf16* __restrict__ W1, const __bf16* __restrict__ W2,
    const float* __restrict__ b0, const float* __restrict__ b1, const float* __restrict__ b2,
    __bf16* out0, __bf16* out1, __bf16* out2)
{
  __shared__ __bf16 As[128 * 64];      // 16 KB; reused as v-transpose buffer in epilogue
  __shared__ __bf16 Bs[3][64 * 64];    // 3 x 8 KB
  const int tid = threadIdx.x;
  const int lane = tid & 63, wid = tid >> 6;
  const int l15 = lane & 15, quad = lane >> 4;
  const int dd = blockIdx.x;
  const int j = dd >> 3;
  const int m0 = ((dd & 7) * 4 + (j & 3)) * 128;   // m fast within XCD -> A-slab reuse
  const int nt = j >> 2;                            // 0..15 = head index
  const int n0 = nt * 64;

  f32x4 acc[3][2][4];
  #pragma unroll
  for (int z = 0; z < 3; z++)
    #pragma unroll
    for (int i = 0; i < 2; i++)
      #pragma unroll
      for (int jj = 0; jj < 4; jj++){
        acc[z][i][jj][0] = 0.f; acc[z][i][jj][1] = 0.f;
        acc[z][i][jj][2] = 0.f; acc[z][i][jj][3] = 0.f;
      }

  const int grow = lane >> 3;
  const int gcol = (((lane & 7) ^ grow) * 8);
  const int sw = (l15 & 7);

  for (int k0 = 0; k0 < E_; k0 += 64){
    __syncthreads();
    #pragma unroll
    for (int r = 0; r < 4; r++){
      int rb = wid * 32 + r * 8;
      glds16(A + (size_t)(m0 + rb + grow) * E_ + k0 + gcol, &As[rb * 64]);
    }
    #pragma unroll
    for (int r = 0; r < 2; r++){
      int rb = wid * 16 + r * 8;
      glds16(W0 + (size_t)(n0 + rb + grow) * E_ + k0 + gcol, &Bs[0][rb * 64]);
      glds16(W1 + (size_t)(n0 + rb + grow) * E_ + k0 + gcol, &Bs[1][rb * 64]);
      glds16(W2 + (size_t)(n0 + rb + grow) * E_ + k0 + gcol, &Bs[2][rb * 64]);
    }
    __syncthreads();
    #pragma unroll
    for (int kq = 0; kq < 2; kq++){
      const int ce = ((kq * 4 + quad) ^ sw) * 8;
      bf16x8 am[2];
      #pragma unroll
      for (int i = 0; i < 2; i++) am[i] = *(const bf16x8*)&As[(wid * 32 + i * 16 + l15) * 64 + ce];
      #pragma unroll
      for (int z = 0; z < 3; z++){
        bf16x8 bn[4];
        #pragma unroll
        for (int jj = 0; jj < 4; jj++) bn[jj] = *(const bf16x8*)&Bs[z][(jj * 16 + l15) * 64 + ce];
        #pragma unroll
        for (int i = 0; i < 2; i++)
          #pragma unroll
          for (int jj = 0; jj < 4; jj++)
            acc[z][i][jj] = __builtin_amdgcn_mfma_f32_16x16x32_bf16(am[i], bn[jj], acc[z][i][jj], 0, 0, 0);
      }
    }
  }

  #pragma unroll
  for (int z = 0; z < 2; z++){
    __bf16* outp = z ? out1 : out0;
    const float* bias = z ? b1 : b0;
    const float scale = z ? 1.0f : 0.125f * LOG2E;
    #pragma unroll
    for (int i = 0; i < 2; i++){
      const int row0 = m0 + wid * 32 + i * 16 + quad * 4;
      #pragma unroll
      for (int jj = 0; jj < 4; jj++){
        const int col = n0 + jj * 16 + l15;
        const float bc = bias[col];
        const int d2 = col & 63;
        #pragma unroll
        for (int r = 0; r < 4; r++){
          float v = (acc[z][i][jj][r] + bc) * scale;
          int row = row0 + r;
          int t = row >> 2, bb = row & 3;
          outp[(size_t)((bb * H_ + nt) * T_ + t) * DH_ + d2] = f2bf(v);
        }
      }
    }
  }

  __syncthreads();
  // v-transpose via swizzled vbuf in As (16 KB). Linear index: nl*256 + bb*64 + tloc*2, XOR (nl&7)<<4.
  char* vb_ = (char*)&As[0];
  {
    const int t_local = 0;  (void)t_local;
    #pragma unroll
    for (int i = 0; i < 2; i++){
      const int tl = wid * 8 + i * 4 + quad;
      #pragma unroll
      for (int jj = 0; jj < 4; jj++){
        const int nl = jj * 16 + l15;
        const float bc = b2[n0 + nl];
        const unsigned swz = (unsigned)((nl & 7) << 4);
        #pragma unroll
        for (int r = 0; r < 4; r++){
          unsigned a = ((unsigned)(nl * 256 + r * 64 + tl * 2)) ^ swz;
          *(__bf16*)(vb_ + a) = f2bf(acc[2][i][jj][r] + bc);
        }
      }
    }
  }
  __syncthreads();
  {
    const int nl = tid >> 2;
    const int bb = tid & 3;
    const unsigned swz = (unsigned)((nl & 7) << 4);
    __bf16* dst = out2 + (size_t)((bb * H_ + nt) * DH_ + nl) * T_ + (m0 >> 2);
    #pragma unroll
    for (int c = 0; c < 4; c++){
      unsigned a = ((unsigned)(nl * 256 + bb * 64 + c * 16)) ^ swz;
      *(bf16x8*)(dst + c * 8) = *(const bf16x8*)(vb_ + a);
    }
  }
}

// ---------------- out-proj GEMM: 64x128 tile, BK=64, XOR-swizzled LDS, XCD grid (512), fp32 write ----------------
__global__ __launch_bounds__(256) void gemm_out(
    const __bf16* __restrict__ A, const __bf16* __restrict__ W,
    const float* __restrict__ bias, float* __restrict__ out)
{
  __shared__ __bf16 As[64 * 64];
  __shared__ __bf16 Bs[128 * 64];
  const int tid = threadIdx.x;
  const int lane = tid & 63, wid = tid >> 6;
  const int l15 = lane & 15, quad = lane >> 4;
  const int wm = wid >> 1, wn = wid & 1;
  const int dd = blockIdx.x;
  const int j = dd >> 3;
  const int m0 = ((dd & 7) * 8 + (j & 7)) * 64;
  const int n0 = (j >> 3) * 128;

  f32x4 acc[2][4];
  #pragma unroll
  for (int i = 0; i < 2; i++)
    #pragma unroll
    for (int jj = 0; jj < 4; jj++){
      acc[i][jj][0] = 0.f; acc[i][jj][1] = 0.f; acc[i][jj][2] = 0.f; acc[i][jj][3] = 0.f;
    }

  const int grow = lane >> 3;
  const int gcol = (((lane & 7) ^ grow) * 8);
  const int sw = (l15 & 7);

  for (int k0 = 0; k0 < E_; k0 += 64){
    __syncthreads();
    #pragma unroll
    for (int r = 0; r < 2; r++){
      int rbA = wid * 16 + r * 8;
      glds16(A + (size_t)(m0 + rbA + grow) * E_ + k0 + gcol, &As[rbA * 64]);
    }
    #pragma unroll
    for (int r = 0; r < 4; r++){
      int rbB = wid * 32 + r * 8;
      glds16(W + (size_t)(n0 + rbB + grow) * E_ + k0 + gcol, &Bs[rbB * 64]);
    }
    __syncthreads();
    #pragma unroll
    for (int kq = 0; kq < 2; kq++){
      const int ce = ((kq * 4 + quad) ^ sw) * 8;
      bf16x8 am[2], bn[4];
      #pragma unroll
      for (int i = 0; i < 2; i++) am[i] = *(const bf16x8*)&As[(wm * 32 + i * 16 + l15) * 64 + ce];
      #pragma unroll
      for (int jj = 0; jj < 4; jj++) bn[jj] = *(const bf16x8*)&Bs[(wn * 64 + jj * 16 + l15) * 64 + ce];
      #pragma unroll
      for (int i = 0; i < 2; i++)
        #pragma unroll
        for (int jj = 0; jj < 4; jj++)
          acc[i][jj] = __builtin_amdgcn_mfma_f32_16x16x32_bf16(am[i], bn[jj], acc[i][jj], 0, 0, 0);
    }
  }

  #pragma unroll
  for (int i = 0; i < 2; i++){
    const int row0 = m0 + wm * 32 + i * 16 + quad * 4;
    #pragma unroll
    for (int jj = 0; jj < 4; jj++){
      const int col = n0 + wn * 64 + jj * 16 + l15;
      const float bc = bias[col];
      #pragma unroll
      for (int r = 0; r < 4; r++)
        out[(size_t)(row0 + r) * E_ + col] = acc[i][jj][r] + bc;
    }
  }
}

// ---------------- flash attention v6: 128 t per block, 256 thr (4 waves), 2 blocks/CU ----------------
// Double-buffered K/V DMA (depth-1 pipeline); ONE __syncthreads per tile.
__global__ __launch_bounds__(256) void attn_kernel(
    const __bf16* __restrict__ qg, const __bf16* __restrict__ kg, const __bf16* __restrict__ vgT,
    const float* __restrict__ gates, const float* __restrict__ tab,
    __bf16* __restrict__ ctx)
{
  const int LDP = 72;                  // P rows padded (written by VALU, b64/b128 path)
  __shared__ __bf16 Ks[2][64 * 64];    // 2 x 8 KB, swizzled chunks: slot c holds global chunk c^(row&7)
  __shared__ __bf16 Vt[2][64 * 64];    // 2 x 8 KB, swizzled (rows = d, cols = s)
  __shared__ __bf16 Pt[4][2][16 * LDP];// per-(wave, tg) P^T
  __shared__ float tabh[2048];         // fp32 rel-bias row for this h

  const int tid = threadIdx.x;
  const int lane = tid & 63, wid = tid >> 6;       // 4 waves
  const int l15 = lane & 15, quad = lane >> 4;
  // XCD swizzle: all 8 t-blocks of a bh share XCD slot d&7
  const int dgrid = blockIdx.x;
  const int j = dgrid >> 3;
  const int bh = (dgrid & 7) + 8 * (j & 7);
  const int tq = j >> 3;               // 0..7 -> t-base tq*128
  const int b = bh >> 4, h = bh & 15;
  const __bf16* qb = qg + (size_t)bh * T_ * DH_;
  const __bf16* kb = kg + (size_t)bh * T_ * DH_;
  const __bf16* vb = vgT + (size_t)bh * DH_ * T_;

  for (int i = tid; i < 2047; i += 256) tabh[i] = tab[h * 2047 + i];

  const int t0w = tq * 128 + wid * 32; // wave owns 32 t = 2 groups of 16
  bf16x8 bq[2][2];
  float g[2];
  int ibase[2];
  #pragma unroll
  for (int tg = 0; tg < 2; tg++){
    int t_lane = t0w + tg * 16 + l15;
    bq[tg][0] = *(const bf16x8*)(qb + (size_t)t_lane * DH_ + quad * 8);
    bq[tg][1] = *(const bf16x8*)(qb + (size_t)t_lane * DH_ + 32 + quad * 8);
    g[tg] = gates[bh * T_ + t_lane];   // already * log2e
    ibase[tg] = 1023 - t_lane;
  }

  const int grow = lane >> 3;                  // staging row within 8-row group
  const int gcol = (((lane & 7) ^ grow) * 8);  // XOR-swizzled source chunk
  const int swf = (l15 & 7);                   // frag-read swizzle key

  float l_run[2] = {0.f, 0.f};
  f32x4 O[2][4];
  #pragma unroll
  for (int tg = 0; tg < 2; tg++)
    #pragma unroll
    for (int mt = 0; mt < 4; mt++){ O[tg][mt][0]=0.f; O[tg][mt][1]=0.f; O[tg][mt][2]=0.f; O[tg][mt][3]=0.f; }

  // prologue: stage s-tile 0 into buffer 0 (wave stages rows [wid*16, wid*16+16))
  #pragma unroll
  for (int r = 0; r < 2; r++){
    int rb = wid * 16 + r * 8;
    glds16(kb + (size_t)(rb + grow) * DH_ + gcol, &Ks[0][rb * 64]);
    glds16(vb + (size_t)(rb + grow) * T_ + gcol, &Vt[0][rb * 64]);
  }
  __syncthreads();                     // implicit vmcnt(0): tile 0 staged

  for (int it = 0; it < 16; it++){
    const int s0 = it * 64;
    const int cur = it & 1;

    // issue next tile's DMA into the other buffer (overlaps with compute below)
    if (it < 15){
      const int sn = s0 + 64;
      #pragma unroll
      for (int r = 0; r < 2; r++){
        int rb = wid * 16 + r * 8;
        glds16(kb + (size_t)(sn + rb + grow) * DH_ + gcol, &Ks[cur ^ 1][rb * 64]);
        glds16(vb + (size_t)(rb + grow) * T_ + sn + gcol, &Vt[cur ^ 1][rb * 64]);
      }
    }

    // S^T = K.Q^T: A=K (shared across tg), B=Q^T. D: S^T[s=nt*16+quad*4+r][t=l15]
    f32x4 S[2][4];
    #pragma unroll
    for (int nt = 0; nt < 4; nt++){
      const int rowb = (nt * 16 + l15) * 64;
      bf16x8 ak0 = *(const bf16x8*)&Ks[cur][rowb + ((quad ^ swf) * 8)];
      bf16x8 ak1 = *(const bf16x8*)&Ks[cur][rowb + (((4 + quad) ^ swf) * 8)];
      #pragma unroll
      for (int tg = 0; tg < 2; tg++){
        f32x4 a; a[0]=0.f; a[1]=0.f; a[2]=0.f; a[3]=0.f;
        a = __builtin_amdgcn_mfma_f32_16x16x32_bf16(ak0, bq[tg][0], a, 0, 0, 0);
        a = __builtin_amdgcn_mfma_f32_16x16x32_bf16(ak1, bq[tg][1], a, 0, 0, 0);
        S[tg][nt] = a;
      }
    }

    // bias + exp2. Saturation: all |s-t| >= 128 in tile -> constant bias (exact bucket clamp).
    const int drel = s0 - t0w;         // wave-uniform
    if (drel >= 160 || drel <= -192){
      const float sv = (drel > 0) ? tabh[1151] : tabh[895];   // rp=+128 / rp=-128 saturated values
      #pragma unroll
      for (int tg = 0; tg < 2; tg++){
        const float cb = g[tg] * sv;
        #pragma unroll
        for (int nt = 0; nt < 4; nt++)
          #pragma unroll
          for (int r = 0; r < 4; r++)
            S[tg][nt][r] = __builtin_amdgcn_exp2f(S[tg][nt][r] + cb);
      }
    } else {
      #pragma unroll
      for (int tg = 0; tg < 2; tg++){
        const int ib = ibase[tg] + s0;
        #pragma unroll
        for (int nt = 0; nt < 4; nt++)
          #pragma unroll
          for (int r = 0; r < 4; r++)
            S[tg][nt][r] = __builtin_amdgcn_exp2f(S[tg][nt][r] + g[tg] * tabh[ib + nt * 16 + quad * 4 + r]);
      }
    }

    // P^T -> wave-local LDS (t-major); denominator off critical path
    #pragma unroll
    for (int tg = 0; tg < 2; tg++){
      __bf16* pw = &Pt[wid][tg][0];
      #pragma unroll
      for (int nt = 0; nt < 4; nt++){
        bf16x4 p;
        p[0] = f2bf_fast(S[tg][nt][0]); p[1] = f2bf_fast(S[tg][nt][1]);
        p[2] = f2bf_fast(S[tg][nt][2]); p[3] = f2bf_fast(S[tg][nt][3]);
        *(bf16x4*)&pw[l15 * LDP + nt * 16 + quad * 4] = p;
      }
      float rs = 0.f;
      #pragma unroll
      for (int nt = 0; nt < 4; nt++) rs += (S[tg][nt][0] + S[tg][nt][1]) + (S[tg][nt][2] + S[tg][nt][3]);
      rs += __shfl_xor(rs, 16, 64);
      rs += __shfl_xor(rs, 32, 64);
      l_run[tg] += rs;
    }

    // O^T += V^T.P^T: A=V^T (shared across tg, swizzled), B=P^T
    #pragma unroll
    for (int ks = 0; ks < 2; ks++){
      bf16x8 bp[2];
      #pragma unroll
      for (int tg = 0; tg < 2; tg++)
        bp[tg] = *(const bf16x8*)&Pt[wid][tg][l15 * LDP + ks * 32 + quad * 8];
      #pragma unroll
      for (int mt = 0; mt < 4; mt++){
        const int rowb = (mt * 16 + l15) * 64;
        bf16x8 av = *(const bf16x8*)&Vt[cur][rowb + (((ks * 4 + quad) ^ swf) * 8)];
        #pragma unroll
        for (int tg = 0; tg < 2; tg++)
          O[tg][mt] = __builtin_amdgcn_mfma_f32_16x16x32_bf16(av, bp[tg], O[tg][mt], 0, 0, 0);
      }
    }

    __syncthreads();  // drains this wave's DMA (next tile staged) + all waves done reading buf[cur]
  }

  // epilogue: ctx[(t*B+b)*E + h*64+d], d = mt*16+quad*4+r
  #pragma unroll
  for (int tg = 0; tg < 2; tg++){
    const int t_lane = t0w + tg * 16 + l15;
    const float inv = 1.f / l_run[tg];
    #pragma unroll
    for (int mt = 0; mt < 4; mt++){
      bf16x4 o;
      o[0] = f2bf(O[tg][mt][0] * inv); o[1] = f2bf(O[tg][mt][1] * inv);
      o[2] = f2bf(O[tg][mt][2] * inv); o[3] = f2bf(O[tg][mt][3] * inv);
      *(bf16x4*)&ctx[(size_t)(t_lane * B_ + b) * E_ + h * DH_ + mt * 16 + quad * 4] = o;
    }
  }
}

extern "C" void kernel_launch(void* const* d_in, const int* in_sizes, int n_in,
                              void* d_out, int out_size, void* d_ws, size_t ws_size,
                              hipStream_t stream)
{
  (void)in_sizes; (void)n_in; (void)out_size; (void)ws_size;
  const float* query    = (const float*)d_in[0];
  const float* q_w      = (const float*)d_in[1];
  const float* q_b      = (const float*)d_in[2];
  const float* k_w      = (const float*)d_in[3];
  const float* k_b      = (const float*)d_in[4];
  const float* v_w      = (const float*)d_in[5];
  const float* v_b      = (const float*)d_in[6];
  const float* out_w    = (const float*)d_in[7];
  const float* out_b    = (const float*)d_in[8];
  const float* rel_bias = (const float*)d_in[9];
  const float* grep_w   = (const float*)d_in[10];
  const float* grep_b   = (const float*)d_in[11];
  const float* grep_a   = (const float*)d_in[12];

  char* ws = (char*)d_ws;
  size_t off = 0;
  __bf16* qbf = (__bf16*)(ws + off); off += (size_t)4096 * 1024 * 2;   // query bf16 (TB, E)
  __bf16* wq  = (__bf16*)(ws + off); off += (size_t)1024 * 1024 * 2;
  __bf16* wk  = (__bf16*)(ws + off); off += (size_t)1024 * 1024 * 2;
  __bf16* wv  = (__bf16*)(ws + off); off += (size_t)1024 * 1024 * 2;
  __bf16* wo  = (__bf16*)(ws + off); off += (size_t)1024 * 1024 * 2;
  __bf16* qh  = (__bf16*)(ws + off); off += (size_t)4096 * 1024 * 2;   // (B,H,T,DH)
  __bf16* kh  = (__bf16*)(ws + off); off += (size_t)4096 * 1024 * 2;   // (B,H,T,DH)
  __bf16* vhT = (__bf16*)(ws + off); off += (size_t)4096 * 1024 * 2;   // (B,H,DH,T)
  __bf16* ctx = (__bf16*)(ws + off); off += (size_t)4096 * 1024 * 2;   // (TB, E)
  float* gates = (float*)(ws + off); off += (size_t)65536 * 4;         // (B*H, T), * log2e
  float* tab   = (float*)(ws + off); off += (size_t)16 * 2047 * 4;     // (H, 2047) fp32

  prep_kernel<<<4480, 256, 0, stream>>>(q_w, k_w, v_w, out_w, wq, wk, wv, wo,
                                        query, grep_w, grep_b, grep_a, gates, qbf,
                                        rel_bias, tab);
  gemm_qkv<<<512, 256, 0, stream>>>(qbf, wq, wk, wv, q_b, k_b, v_b, qh, kh, vhT);
  attn_kernel<<<512, 256, 0, stream>>>(qh, kh, vhT, gates, tab, ctx);
  gemm_out<<<512, 256, 0, stream>>>(ctx, wo, out_b, (float*)d_out);
}

// Round 9
// 174.979 us; speedup vs baseline: 1.2285x; 1.1184x over previous
//
#include <hip/hip_runtime.h>
#include <math.h>

// Problem constants (reference: T,B,E,H = 1024,4,1024,16; DH=64; 32 buckets, max_dist 128)
#define T_ 1024
#define B_ 4
#define E_ 1024
#define H_ 16
#define DH_ 64

#define LOG2E 1.44269504088896f

typedef __attribute__((ext_vector_type(8))) __bf16 bf16x8;
typedef __attribute__((ext_vector_type(4))) __bf16 bf16x4;
typedef __attribute__((ext_vector_type(4))) float f32x4;

// fp32 -> bf16 round-to-nearest-even
__device__ __forceinline__ __bf16 f2bf(float x){
  union { unsigned short u; __bf16 b; } cv;
  unsigned u32 = __float_as_uint(x);
  cv.u = (unsigned short)((u32 + 0x7fffu + ((u32 >> 16) & 1u)) >> 16);
  return cv.b;
}
// fp32 -> bf16 round-half-up (cheaper; used only for P >= 0)
__device__ __forceinline__ __bf16 f2bf_fast(float x){
  union { unsigned short u; __bf16 b; } cv;
  cv.u = (unsigned short)((__float_as_uint(x) + 0x8000u) >> 16);
  return cv.b;
}

// async global->LDS, 16B per lane; LDS dest is wave-uniform base + lane*16 (m97/m104)
__device__ __forceinline__ void glds16(const void* g, void* l){
  __builtin_amdgcn_global_load_lds(
      (__attribute__((address_space(1))) void*)(void*)g,
      (__attribute__((address_space(3))) void*)l,
      16, 0, 0);
}

// ---------------- prep v2: coalesced + ILP restructure ----------------
// Old prep ran at 947 GB/s (12% HBM), 41.7 us -- latency-bound: gates section had 256 blocks
// (1/CU), serialized loads (VGPR=32), and 128B-strided query reads / qbf writes.
// New layout: blocks [0,1024) = Q section, one t per block: each thread reads 16 consecutive
// floats (4 coalesced float4, ILP 4), converts+stores qbf coalesced, AND computes gate dot
// partials from the same registers (gw in LDS, 4-lane shfl_xor reduce).
// Blocks [1024,2048) = weight cvt, 4 float4/thread (ILP 4). Blocks [2048,2176) = tab (unchanged).
__global__ __launch_bounds__(256) void prep_kernel(
    const float* __restrict__ q_w, const float* __restrict__ k_w,
    const float* __restrict__ v_w, const float* __restrict__ out_w,
    __bf16* __restrict__ wq, __bf16* __restrict__ wk,
    __bf16* __restrict__ wv, __bf16* __restrict__ wo,
    const float* __restrict__ query, const float* __restrict__ gw,
    const float* __restrict__ gb, const float* __restrict__ ga,
    float* __restrict__ gates, __bf16* __restrict__ qbf,
    const float* __restrict__ rel_bias, float* __restrict__ tab)
{
  const int bid = blockIdx.x;
  const int tid = threadIdx.x;
  if (bid < 1024){
    // ---- Q section: query cvt -> qbf + gates, one t per block ----
    __shared__ float gws[512];                 // gw is (8,64) = 512 floats
    const int t = bid;
    const float* q = query + (size_t)t * 4096; // (T, B*E) row
    __bf16* qo = qbf + (size_t)t * 4096;
    for (int i = tid; i < 512; i += 256) gws[i] = gw[i];
    __syncthreads();
    const float4* qv = (const float4*)q + tid * 4;
    float4 v0 = qv[0], v1 = qv[1], v2 = qv[2], v3 = qv[3];   // 16 consecutive floats
    bf16x8 o0, o1;
    o0[0]=f2bf(v0.x); o0[1]=f2bf(v0.y); o0[2]=f2bf(v0.z); o0[3]=f2bf(v0.w);
    o0[4]=f2bf(v1.x); o0[5]=f2bf(v1.y); o0[6]=f2bf(v1.z); o0[7]=f2bf(v1.w);
    o1[0]=f2bf(v2.x); o1[1]=f2bf(v2.y); o1[2]=f2bf(v2.z); o1[3]=f2bf(v2.w);
    o1[4]=f2bf(v3.x); o1[5]=f2bf(v3.y); o1[6]=f2bf(v3.z); o1[7]=f2bf(v3.w);
    *(bf16x8*)(qo + tid * 16) = o0;            // fully coalesced 32B/thread
    *(bf16x8*)(qo + tid * 16 + 8) = o1;
    // gate partials: thread owns d-quarter p of row bh = tid>>2
    const int p = tid & 3;
    float g[8];
    #pragma unroll
    for (int e = 0; e < 8; e++){
      const float* w = &gws[e * 64 + p * 16];
      float s0 = v0.x*w[0]  + v0.y*w[1]  + v0.z*w[2]  + v0.w*w[3];
      float s1 = v1.x*w[4]  + v1.y*w[5]  + v1.z*w[6]  + v1.w*w[7];
      float s2 = v2.x*w[8]  + v2.y*w[9]  + v2.z*w[10] + v2.w*w[11];
      float s3 = v3.x*w[12] + v3.y*w[13] + v3.z*w[14] + v3.w*w[15];
      g[e] = (s0 + s1) + (s2 + s3);
    }
    #pragma unroll
    for (int e = 0; e < 8; e++){
      g[e] += __shfl_xor(g[e], 1, 64);
      g[e] += __shfl_xor(g[e], 2, 64);
    }
    if (p == 0){
      const int bh = tid >> 2;                 // 0..63
      const int h = bh & 15;
      float a0 = ((g[0]+gb[0]) + (g[1]+gb[1])) + ((g[2]+gb[2]) + (g[3]+gb[3]));
      float a1 = ((g[4]+gb[4]) + (g[5]+gb[5])) + ((g[6]+gb[6]) + (g[7]+gb[7]));
      float sa = 1.f / (1.f + __expf(-a0));
      float sb = 1.f / (1.f + __expf(-a1));
      gates[bh * T_ + t] = (sa * (sb * ga[h] - 1.0f) + 2.0f) * LOG2E;   // pre-scaled for exp2
    }
  } else if (bid < 2048){
    // ---- weight cvt: 256 blocks per matrix, 16 floats/thread (4 coalesced float4) ----
    const int lb = bid - 1024;
    const float* a; __bf16* o;
    switch (lb >> 8){
      case 0: a = q_w;  o = wq; break;
      case 1: a = k_w;  o = wk; break;
      case 2: a = v_w;  o = wv; break;
      default: a = out_w; o = wo; break;
    }
    const int base = (lb & 255) * 4096;
    float4 v[4];
    #pragma unroll
    for (int c = 0; c < 4; c++) v[c] = *(const float4*)(a + base + c * 1024 + tid * 4);
    #pragma unroll
    for (int c = 0; c < 4; c++){
      bf16x4 r;
      r[0] = f2bf(v[c].x); r[1] = f2bf(v[c].y); r[2] = f2bf(v[c].z); r[3] = f2bf(v[c].w);
      *(bf16x4*)(o + base + c * 1024 + tid * 4) = r;
    }
  } else {
    // ---- tab (unchanged math) ----
    int tb = bid - 2048;               // 0..127
    int h = tb >> 3;
    int i = (tb & 7) * 256 + tid;
    if (i < 2047){
      int rp = i - 1023;
      int base = rp > 0 ? 16 : 0;
      int arp = rp < 0 ? -rp : rp;
      int off;
      if (arp < 8) off = arp;
      else {
        float val = (logf((float)arp * 0.125f) / 2.772588722239781f) * 8.0f;
        int lg = (int)val;
        off = 8 + (lg > 7 ? 7 : lg);
      }
      tab[h * 2047 + i] = rel_bias[(base + off) * H_ + h];   // fp32 now
    }
  }
}

// ---------------- fused QKV GEMM (round-0 2-phase, best measured): 128m x 64n x {q,k,v} ----------------
// v-epilogue vbuf XOR-swizzled: elem (nl,bb,tloc) at byte (nl*256 + bb*64 + tloc*2) ^ ((nl&7)<<4).
__global__ __launch_bounds__(256, 2) void gemm_qkv(
    const __bf16* __restrict__ A,
    const __bf16* __restrict__ W0, const __bf16* __restrict__ W1, const __bf16* __restrict__ W2,
    const float* __restrict__ b0, const float* __restrict__ b1, const float* __restrict__ b2,
    __bf16* out0, __bf16* out1, __bf16* out2)
{
  __shared__ __bf16 As[128 * 64];      // 16 KB; reused as v-transpose buffer in epilogue
  __shared__ __bf16 Bs[3][64 * 64];    // 3 x 8 KB
  const int tid = threadIdx.x;
  const int lane = tid & 63, wid = tid >> 6;
  const int l15 = lane & 15, quad = lane >> 4;
  const int dd = blockIdx.x;
  const int j = dd >> 3;
  const int m0 = ((dd & 7) * 4 + (j & 3)) * 128;   // m fast within XCD -> A-slab reuse
  const int nt = j >> 2;                            // 0..15 = head index
  const int n0 = nt * 64;

  f32x4 acc[3][2][4];
  #pragma unroll
  for (int z = 0; z < 3; z++)
    #pragma unroll
    for (int i = 0; i < 2; i++)
      #pragma unroll
      for (int jj = 0; jj < 4; jj++){
        acc[z][i][jj][0] = 0.f; acc[z][i][jj][1] = 0.f;
        acc[z][i][jj][2] = 0.f; acc[z][i][jj][3] = 0.f;
      }

  const int grow = lane >> 3;
  const int gcol = (((lane & 7) ^ grow) * 8);
  const int sw = (l15 & 7);

  for (int k0 = 0; k0 < E_; k0 += 64){
    __syncthreads();
    #pragma unroll
    for (int r = 0; r < 4; r++){
      int rb = wid * 32 + r * 8;
      glds16(A + (size_t)(m0 + rb + grow) * E_ + k0 + gcol, &As[rb * 64]);
    }
    #pragma unroll
    for (int r = 0; r < 2; r++){
      int rb = wid * 16 + r * 8;
      glds16(W0 + (size_t)(n0 + rb + grow) * E_ + k0 + gcol, &Bs[0][rb * 64]);
      glds16(W1 + (size_t)(n0 + rb + grow) * E_ + k0 + gcol, &Bs[1][rb * 64]);
      glds16(W2 + (size_t)(n0 + rb + grow) * E_ + k0 + gcol, &Bs[2][rb * 64]);
    }
    __syncthreads();
    #pragma unroll
    for (int kq = 0; kq < 2; kq++){
      const int ce = ((kq * 4 + quad) ^ sw) * 8;
      bf16x8 am[2];
      #pragma unroll
      for (int i = 0; i < 2; i++) am[i] = *(const bf16x8*)&As[(wid * 32 + i * 16 + l15) * 64 + ce];
      #pragma unroll
      for (int z = 0; z < 3; z++){
        bf16x8 bn[4];
        #pragma unroll
        for (int jj = 0; jj < 4; jj++) bn[jj] = *(const bf16x8*)&Bs[z][(jj * 16 + l15) * 64 + ce];
        #pragma unroll
        for (int i = 0; i < 2; i++)
          #pragma unroll
          for (int jj = 0; jj < 4; jj++)
            acc[z][i][jj] = __builtin_amdgcn_mfma_f32_16x16x32_bf16(am[i], bn[jj], acc[z][i][jj], 0, 0, 0);
      }
    }
  }

  #pragma unroll
  for (int z = 0; z < 2; z++){
    __bf16* outp = z ? out1 : out0;
    const float* bias = z ? b1 : b0;
    const float scale = z ? 1.0f : 0.125f * LOG2E;
    #pragma unroll
    for (int i = 0; i < 2; i++){
      const int row0 = m0 + wid * 32 + i * 16 + quad * 4;
      #pragma unroll
      for (int jj = 0; jj < 4; jj++){
        const int col = n0 + jj * 16 + l15;
        const float bc = bias[col];
        const int d2 = col & 63;
        #pragma unroll
        for (int r = 0; r < 4; r++){
          float v = (acc[z][i][jj][r] + bc) * scale;
          int row = row0 + r;
          int t = row >> 2, bb = row & 3;
          outp[(size_t)((bb * H_ + nt) * T_ + t) * DH_ + d2] = f2bf(v);
        }
      }
    }
  }

  __syncthreads();
  // v-transpose via swizzled vbuf in As (16 KB). Linear index: nl*256 + bb*64 + tloc*2, XOR (nl&7)<<4.
  char* vb_ = (char*)&As[0];
  {
    #pragma unroll
    for (int i = 0; i < 2; i++){
      const int tl = wid * 8 + i * 4 + quad;
      #pragma unroll
      for (int jj = 0; jj < 4; jj++){
        const int nl = jj * 16 + l15;
        const float bc = b2[n0 + nl];
        const unsigned swz = (unsigned)((nl & 7) << 4);
        #pragma unroll
        for (int r = 0; r < 4; r++){
          unsigned a = ((unsigned)(nl * 256 + r * 64 + tl * 2)) ^ swz;
          *(__bf16*)(vb_ + a) = f2bf(acc[2][i][jj][r] + bc);
        }
      }
    }
  }
  __syncthreads();
  {
    const int nl = tid >> 2;
    const int bb = tid & 3;
    const unsigned swz = (unsigned)((nl & 7) << 4);
    __bf16* dst = out2 + (size_t)((bb * H_ + nt) * DH_ + nl) * T_ + (m0 >> 2);
    #pragma unroll
    for (int c = 0; c < 4; c++){
      unsigned a = ((unsigned)(nl * 256 + bb * 64 + c * 16)) ^ swz;
      *(bf16x8*)(dst + c * 8) = *(const bf16x8*)(vb_ + a);
    }
  }
}

// ---------------- out-proj GEMM: 64x128 tile, BK=64, XOR-swizzled LDS, XCD grid (512), fp32 write ----------------
__global__ __launch_bounds__(256) void gemm_out(
    const __bf16* __restrict__ A, const __bf16* __restrict__ W,
    const float* __restrict__ bias, float* __restrict__ out)
{
  __shared__ __bf16 As[64 * 64];
  __shared__ __bf16 Bs[128 * 64];
  const int tid = threadIdx.x;
  const int lane = tid & 63, wid = tid >> 6;
  const int l15 = lane & 15, quad = lane >> 4;
  const int wm = wid >> 1, wn = wid & 1;
  const int dd = blockIdx.x;
  const int j = dd >> 3;
  const int m0 = ((dd & 7) * 8 + (j & 7)) * 64;
  const int n0 = (j >> 3) * 128;

  f32x4 acc[2][4];
  #pragma unroll
  for (int i = 0; i < 2; i++)
    #pragma unroll
    for (int jj = 0; jj < 4; jj++){
      acc[i][jj][0] = 0.f; acc[i][jj][1] = 0.f; acc[i][jj][2] = 0.f; acc[i][jj][3] = 0.f;
    }

  const int grow = lane >> 3;
  const int gcol = (((lane & 7) ^ grow) * 8);
  const int sw = (l15 & 7);

  for (int k0 = 0; k0 < E_; k0 += 64){
    __syncthreads();
    #pragma unroll
    for (int r = 0; r < 2; r++){
      int rbA = wid * 16 + r * 8;
      glds16(A + (size_t)(m0 + rbA + grow) * E_ + k0 + gcol, &As[rbA * 64]);
    }
    #pragma unroll
    for (int r = 0; r < 4; r++){
      int rbB = wid * 32 + r * 8;
      glds16(W + (size_t)(n0 + rbB + grow) * E_ + k0 + gcol, &Bs[rbB * 64]);
    }
    __syncthreads();
    #pragma unroll
    for (int kq = 0; kq < 2; kq++){
      const int ce = ((kq * 4 + quad) ^ sw) * 8;
      bf16x8 am[2], bn[4];
      #pragma unroll
      for (int i = 0; i < 2; i++) am[i] = *(const bf16x8*)&As[(wm * 32 + i * 16 + l15) * 64 + ce];
      #pragma unroll
      for (int jj = 0; jj < 4; jj++) bn[jj] = *(const bf16x8*)&Bs[(wn * 64 + jj * 16 + l15) * 64 + ce];
      #pragma unroll
      for (int i = 0; i < 2; i++)
        #pragma unroll
        for (int jj = 0; jj < 4; jj++)
          acc[i][jj] = __builtin_amdgcn_mfma_f32_16x16x32_bf16(am[i], bn[jj], acc[i][jj], 0, 0, 0);
    }
  }

  #pragma unroll
  for (int i = 0; i < 2; i++){
    const int row0 = m0 + wm * 32 + i * 16 + quad * 4;
    #pragma unroll
    for (int jj = 0; jj < 4; jj++){
      const int col = n0 + wn * 64 + jj * 16 + l15;
      const float bc = bias[col];
      #pragma unroll
      for (int r = 0; r < 4; r++)
        out[(size_t)(row0 + r) * E_ + col] = acc[i][jj][r] + bc;
    }
  }
}

// ---------------- flash attention v6: 128 t per block, 256 thr (4 waves), 2 blocks/CU ----------------
// Double-buffered K/V DMA (depth-1 pipeline); ONE __syncthreads per tile.
__global__ __launch_bounds__(256) void attn_kernel(
    const __bf16* __restrict__ qg, const __bf16* __restrict__ kg, const __bf16* __restrict__ vgT,
    const float* __restrict__ gates, const float* __restrict__ tab,
    __bf16* __restrict__ ctx)
{
  const int LDP = 72;                  // P rows padded (written by VALU, b64/b128 path)
  __shared__ __bf16 Ks[2][64 * 64];    // 2 x 8 KB, swizzled chunks: slot c holds global chunk c^(row&7)
  __shared__ __bf16 Vt[2][64 * 64];    // 2 x 8 KB, swizzled (rows = d, cols = s)
  __shared__ __bf16 Pt[4][2][16 * LDP];// per-(wave, tg) P^T
  __shared__ float tabh[2048];         // fp32 rel-bias row for this h

  const int tid = threadIdx.x;
  const int lane = tid & 63, wid = tid >> 6;       // 4 waves
  const int l15 = lane & 15, quad = lane >> 4;
  // XCD swizzle: all 8 t-blocks of a bh share XCD slot d&7
  const int dgrid = blockIdx.x;
  const int j = dgrid >> 3;
  const int bh = (dgrid & 7) + 8 * (j & 7);
  const int tq = j >> 3;               // 0..7 -> t-base tq*128
  const int b = bh >> 4, h = bh & 15;
  const __bf16* qb = qg + (size_t)bh * T_ * DH_;
  const __bf16* kb = kg + (size_t)bh * T_ * DH_;
  const __bf16* vb = vgT + (size_t)bh * DH_ * T_;

  for (int i = tid; i < 2047; i += 256) tabh[i] = tab[h * 2047 + i];

  const int t0w = tq * 128 + wid * 32; // wave owns 32 t = 2 groups of 16
  bf16x8 bq[2][2];
  float g[2];
  int ibase[2];
  #pragma unroll
  for (int tg = 0; tg < 2; tg++){
    int t_lane = t0w + tg * 16 + l15;
    bq[tg][0] = *(const bf16x8*)(qb + (size_t)t_lane * DH_ + quad * 8);
    bq[tg][1] = *(const bf16x8*)(qb + (size_t)t_lane * DH_ + 32 + quad * 8);
    g[tg] = gates[bh * T_ + t_lane];   // already * log2e
    ibase[tg] = 1023 - t_lane;
  }

  const int grow = lane >> 3;                  // staging row within 8-row group
  const int gcol = (((lane & 7) ^ grow) * 8);  // XOR-swizzled source chunk
  const int swf = (l15 & 7);                   // frag-read swizzle key

  float l_run[2] = {0.f, 0.f};
  f32x4 O[2][4];
  #pragma unroll
  for (int tg = 0; tg < 2; tg++)
    #pragma unroll
    for (int mt = 0; mt < 4; mt++){ O[tg][mt][0]=0.f; O[tg][mt][1]=0.f; O[tg][mt][2]=0.f; O[tg][mt][3]=0.f; }

  // prologue: stage s-tile 0 into buffer 0 (wave stages rows [wid*16, wid*16+16))
  #pragma unroll
  for (int r = 0; r < 2; r++){
    int rb = wid * 16 + r * 8;
    glds16(kb + (size_t)(rb + grow) * DH_ + gcol, &Ks[0][rb * 64]);
    glds16(vb + (size_t)(rb + grow) * T_ + gcol, &Vt[0][rb * 64]);
  }
  __syncthreads();                     // implicit vmcnt(0): tile 0 staged

  for (int it = 0; it < 16; it++){
    const int s0 = it * 64;
    const int cur = it & 1;

    // issue next tile's DMA into the other buffer (overlaps with compute below)
    if (it < 15){
      const int sn = s0 + 64;
      #pragma unroll
      for (int r = 0; r < 2; r++){
        int rb = wid * 16 + r * 8;
        glds16(kb + (size_t)(sn + rb + grow) * DH_ + gcol, &Ks[cur ^ 1][rb * 64]);
        glds16(vb + (size_t)(rb + grow) * T_ + sn + gcol, &Vt[cur ^ 1][rb * 64]);
      }
    }

    // S^T = K.Q^T: A=K (shared across tg), B=Q^T. D: S^T[s=nt*16+quad*4+r][t=l15]
    f32x4 S[2][4];
    #pragma unroll
    for (int nt = 0; nt < 4; nt++){
      const int rowb = (nt * 16 + l15) * 64;
      bf16x8 ak0 = *(const bf16x8*)&Ks[cur][rowb + ((quad ^ swf) * 8)];
      bf16x8 ak1 = *(const bf16x8*)&Ks[cur][rowb + (((4 + quad) ^ swf) * 8)];
      #pragma unroll
      for (int tg = 0; tg < 2; tg++){
        f32x4 a; a[0]=0.f; a[1]=0.f; a[2]=0.f; a[3]=0.f;
        a = __builtin_amdgcn_mfma_f32_16x16x32_bf16(ak0, bq[tg][0], a, 0, 0, 0);
        a = __builtin_amdgcn_mfma_f32_16x16x32_bf16(ak1, bq[tg][1], a, 0, 0, 0);
        S[tg][nt] = a;
      }
    }

    // bias + exp2. Saturation: all |s-t| >= 128 in tile -> constant bias (exact bucket clamp).
    const int drel = s0 - t0w;         // wave-uniform
    if (drel >= 160 || drel <= -192){
      const float sv = (drel > 0) ? tabh[1151] : tabh[895];   // rp=+128 / rp=-128 saturated values
      #pragma unroll
      for (int tg = 0; tg < 2; tg++){
        const float cb = g[tg] * sv;
        #pragma unroll
        for (int nt = 0; nt < 4; nt++)
          #pragma unroll
          for (int r = 0; r < 4; r++)
            S[tg][nt][r] = __builtin_amdgcn_exp2f(S[tg][nt][r] + cb);
      }
    } else {
      #pragma unroll
      for (int tg = 0; tg < 2; tg++){
        const int ib = ibase[tg] + s0;
        #pragma unroll
        for (int nt = 0; nt < 4; nt++)
          #pragma unroll
          for (int r = 0; r < 4; r++)
            S[tg][nt][r] = __builtin_amdgcn_exp2f(S[tg][nt][r] + g[tg] * tabh[ib + nt * 16 + quad * 4 + r]);
      }
    }

    // P^T -> wave-local LDS (t-major); denominator off critical path
    #pragma unroll
    for (int tg = 0; tg < 2; tg++){
      __bf16* pw = &Pt[wid][tg][0];
      #pragma unroll
      for (int nt = 0; nt < 4; nt++){
        bf16x4 p;
        p[0] = f2bf_fast(S[tg][nt][0]); p[1] = f2bf_fast(S[tg][nt][1]);
        p[2] = f2bf_fast(S[tg][nt][2]); p[3] = f2bf_fast(S[tg][nt][3]);
        *(bf16x4*)&pw[l15 * LDP + nt * 16 + quad * 4] = p;
      }
      float rs = 0.f;
      #pragma unroll
      for (int nt = 0; nt < 4; nt++) rs += (S[tg][nt][0] + S[tg][nt][1]) + (S[tg][nt][2] + S[tg][nt][3]);
      rs += __shfl_xor(rs, 16, 64);
      rs += __shfl_xor(rs, 32, 64);
      l_run[tg] += rs;
    }

    // O^T += V^T.P^T: A=V^T (shared across tg, swizzled), B=P^T
    #pragma unroll
    for (int ks = 0; ks < 2; ks++){
      bf16x8 bp[2];
      #pragma unroll
      for (int tg = 0; tg < 2; tg++)
        bp[tg] = *(const bf16x8*)&Pt[wid][tg][l15 * LDP + ks * 32 + quad * 8];
      #pragma unroll
      for (int mt = 0; mt < 4; mt++){
        const int rowb = (mt * 16 + l15) * 64;
        bf16x8 av = *(const bf16x8*)&Vt[cur][rowb + (((ks * 4 + quad) ^ swf) * 8)];
        #pragma unroll
        for (int tg = 0; tg < 2; tg++)
          O[tg][mt] = __builtin_amdgcn_mfma_f32_16x16x32_bf16(av, bp[tg], O[tg][mt], 0, 0, 0);
      }
    }

    __syncthreads();  // drains this wave's DMA (next tile staged) + all waves done reading buf[cur]
  }

  // epilogue: ctx[(t*B+b)*E + h*64+d], d = mt*16+quad*4+r
  #pragma unroll
  for (int tg = 0; tg < 2; tg++){
    const int t_lane = t0w + tg * 16 + l15;
    const float inv = 1.f / l_run[tg];
    #pragma unroll
    for (int mt = 0; mt < 4; mt++){
      bf16x4 o;
      o[0] = f2bf(O[tg][mt][0] * inv); o[1] = f2bf(O[tg][mt][1] * inv);
      o[2] = f2bf(O[tg][mt][2] * inv); o[3] = f2bf(O[tg][mt][3] * inv);
      *(bf16x4*)&ctx[(size_t)(t_lane * B_ + b) * E_ + h * DH_ + mt * 16 + quad * 4] = o;
    }
  }
}

extern "C" void kernel_launch(void* const* d_in, const int* in_sizes, int n_in,
                              void* d_out, int out_size, void* d_ws, size_t ws_size,
                              hipStream_t stream)
{
  (void)in_sizes; (void)n_in; (void)out_size; (void)ws_size;
  const float* query    = (const float*)d_in[0];
  const float* q_w      = (const float*)d_in[1];
  const float* q_b      = (const float*)d_in[2];
  const float* k_w      = (const float*)d_in[3];
  const float* k_b      = (const float*)d_in[4];
  const float* v_w      = (const float*)d_in[5];
  const float* v_b      = (const float*)d_in[6];
  const float* out_w    = (const float*)d_in[7];
  const float* out_b    = (const float*)d_in[8];
  const float* rel_bias = (const float*)d_in[9];
  const float* grep_w   = (const float*)d_in[10];
  const float* grep_b   = (const float*)d_in[11];
  const float* grep_a   = (const float*)d_in[12];

  char* ws = (char*)d_ws;
  size_t off = 0;
  __bf16* qbf = (__bf16*)(ws + off); off += (size_t)4096 * 1024 * 2;   // query bf16 (TB, E)
  __bf16* wq  = (__bf16*)(ws + off); off += (size_t)1024 * 1024 * 2;
  __bf16* wk  = (__bf16*)(ws + off); off += (size_t)1024 * 1024 * 2;
  __bf16* wv  = (__bf16*)(ws + off); off += (size_t)1024 * 1024 * 2;
  __bf16* wo  = (__bf16*)(ws + off); off += (size_t)1024 * 1024 * 2;
  __bf16* qh  = (__bf16*)(ws + off); off += (size_t)4096 * 1024 * 2;   // (B,H,T,DH)
  __bf16* kh  = (__bf16*)(ws + off); off += (size_t)4096 * 1024 * 2;   // (B,H,T,DH)
  __bf16* vhT = (__bf16*)(ws + off); off += (size_t)4096 * 1024 * 2;   // (B,H,DH,T)
  __bf16* ctx = (__bf16*)(ws + off); off += (size_t)4096 * 1024 * 2;   // (TB, E)
  float* gates = (float*)(ws + off); off += (size_t)65536 * 4;         // (B*H, T), * log2e
  float* tab   = (float*)(ws + off); off += (size_t)16 * 2047 * 4;     // (H, 2047) fp32

  prep_kernel<<<2176, 256, 0, stream>>>(q_w, k_w, v_w, out_w, wq, wk, wv, wo,
                                        query, grep_w, grep_b, grep_a, gates, qbf,
                                        rel_bias, tab);
  gemm_qkv<<<512, 256, 0, stream>>>(qbf, wq, wk, wv, q_b, k_b, v_b, qh, kh, vhT);
  attn_kernel<<<512, 256, 0, stream>>>(qh, kh, vhT, gates, tab, ctx);
  gemm_out<<<512, 256, 0, stream>>>(ctx, wo, out_b, (float*)d_out);
}